// Round 6
// baseline (2621.741 us; speedup 1.0000x reference)
//
#include <hip/hip_runtime.h>
#include <cstdint>
#include <cstddef>

#define NROWS 32768
#define DDIM 256
#define KCODES 4096

// ---------------- ws layout (float offsets) ----------------
#define WS_LOSS 0
#define WS_BINS 1
#define WS_ESUM (1 + KCODES)
#define WS_N (WS_ESUM + KCODES * DDIM)
#define WS_XSQ (WS_N + 1)
#define WS_ESQ (WS_XSQ + NROWS)
#define WS_IDX (WS_ESQ + KCODES)

// gcc _mm512_reduce_add_ps pairing tree (numpy npyv_sum_f32 on AVX512)
__device__ __forceinline__ float hsum16_np(const float a[16]) {
    float t3[8];
#pragma unroll
    for (int m = 0; m < 8; ++m) t3[m] = __fadd_rn(a[m + 8], a[m]);
    float t6[4];
#pragma unroll
    for (int m = 0; m < 4; ++m) t6[m] = __fadd_rn(t3[m + 4], t3[m]);
    return __fadd_rn(__fadd_rn(t6[0], t6[2]), __fadd_rn(t6[1], t6[3]));
}

// numpy FLOAT_pairwise_sum of squares, 128-element SIMD block (AVX512):
// 8 zmm loads, lane-wise tree ((v0+v1)+(v2+v3))+((v4+v5)+(v6+v7)), horizontal gcc tree
__device__ __forceinline__ float np_sum_sq_128(const float* a) {
    float t[16];
#pragma unroll
    for (int l = 0; l < 16; ++l) {
        float m0 = __fmul_rn(a[l], a[l]);
        float m1 = __fmul_rn(a[16 + l], a[16 + l]);
        float m2 = __fmul_rn(a[32 + l], a[32 + l]);
        float m3 = __fmul_rn(a[48 + l], a[48 + l]);
        float m4 = __fmul_rn(a[64 + l], a[64 + l]);
        float m5 = __fmul_rn(a[80 + l], a[80 + l]);
        float m6 = __fmul_rn(a[96 + l], a[96 + l]);
        float m7 = __fmul_rn(a[112 + l], a[112 + l]);
        float s01 = __fadd_rn(m0, m1);
        float s23 = __fadd_rn(m2, m3);
        float s45 = __fadd_rn(m4, m5);
        float s67 = __fadd_rn(m6, m7);
        t[l] = __fadd_rn(__fadd_rn(s01, s23), __fadd_rn(s45, s67));
    }
    return hsum16_np(t);
}

__global__ void k_rownorm(const float* __restrict__ src, float* __restrict__ dst, int rows) {
    int r = blockIdx.x * blockDim.x + threadIdx.x;
    if (r < rows) {
        const float* p = src + ((size_t)r << 8);
        // numpy pairwise recursion: 256 -> 128 + 128
        dst[r] = __fadd_rn(np_sum_sq_128(p), np_sum_sq_128(p + 128));
    }
}

// DMA one 64-row x 64-col embed chunk into an LDS buffer via global_load_lds.
// LDS layout is linear (DMA writes wave-uniform base + lane*16); the XOR bank
// swizzle (col ^= (row&7)<<2, dword units) is imposed by pre-swizzling the
// per-lane GLOBAL source address (rule #21: source perm == read perm).
__device__ __forceinline__ void dma_chunk(const float* __restrict__ embed, int k0, int c,
                                          int w, int L, float* lds_buf) {
#pragma unroll
    for (int p = 0; p < 4; ++p) {
        const int seg = (w << 2) + p;                       // 0..15, wave-uniform
        const int row = (seg << 2) + (L >> 4);              // 0..63
        const int col = ((L & 15) << 2) ^ ((row & 7) << 2); // pre-swizzled source col
        const float* src = embed + (((size_t)(k0 + row)) << 8) + (c << 6) + col;
        __builtin_amdgcn_global_load_lds(
            (const __attribute__((address_space(1))) void*)src,
            (__attribute__((address_space(3))) void*)(lds_buf + (seg << 8)), 16, 0, 0);
    }
}

// fused dist + argmin. block tile: 32 rows x 64 cols, 256 threads, micro 2x4,
// 16 lane-accumulators per pair (mimics np.einsum single-vaccum FMA chain).
//
// Occupancy history:
//   launch_bounds(256,2): VGPR capped 128 -> acc spills to scratch, 607MB wr.
//   launch_bounds(256,1): no spill (116 VGPR) but 1 block/CU -> regressed.
//   waves_per_eu(2):      2 blocks/CU, 116 VGPR, 1388us, VALUBusy 48%.
//   reg-prefetch (R3/R4): allocator chased the 128-VGPR bucket both times
//     (scratch spill 103GB / LDS spill +16KB, 1.5e8 bank conflicts). VGPR
//     prefetch is unlandable here.
// R5: prefetch in hardware instead — global_load_lds DMA double-buffer of es
// (zero persistent VGPRs), one __syncthreads per phase (its builtin vmcnt(0)
// drain is the DMA wait). es/xs unpadded + XOR bank swizzle (2-way max).
__global__ __attribute__((amdgpu_flat_work_group_size(256, 256), amdgpu_waves_per_eu(2)))
void k_argmin(const float* __restrict__ x,
              const float* __restrict__ embed,
              const float* __restrict__ xsq,
              const float* __restrict__ esq,
              int* __restrict__ out_idx) {
    __shared__ __align__(16) float xs[32 * 256];   // 32KB, swizzled
    __shared__ __align__(16) float es2[2 * 4096];  // 2 x 16KB DMA double buffer, swizzled
    unsigned long long* red = (unsigned long long*)xs;  // aliased after last barrier

    const int tid = threadIdx.x;
    const int tc = tid & 15;
    const int tr = tid >> 4;
    const int w = tid >> 6;
    const int L = tid & 63;
    const int n0 = blockIdx.x * 32;
    const int xkey = (tr & 7) << 2;   // xs read swizzle key (rows tr, tr+16 share it)
    const int eskey = (tc & 7) << 2;  // es read swizzle key (row = tc+16*j2, &7 == tc&7)

    // prologue: DMA chunk (kt=0,c=0) into buf0; stage xs with swizzled writes
    dma_chunk(embed, 0, 0, w, L, &es2[0]);
#pragma unroll
    for (int p = 0; p < 8; ++p) {
        int v = tid + p * 256;
        int r = v >> 6;
        int c4 = (v & 63) << 2;
        const float4 f = *reinterpret_cast<const float4*>(x + ((size_t)(n0 + r) << 8) + c4);
        *reinterpret_cast<float4*>(&xs[(r << 8) + (c4 ^ ((r & 7) << 2))]) = f;
    }

    const float xq0 = xsq[n0 + tr];
    const float xq1 = xsq[n0 + tr + 16];

    unsigned long long best0 = ~0ull, best1 = ~0ull;

    __syncthreads();  // xs staged + chunk0 DMA drained (vmcnt(0) in barrier)

    for (int kt = 0; kt < KCODES / 64; ++kt) {
        const int k0 = kt * 64;
        float acc[2][4][16];
#pragma unroll
        for (int i = 0; i < 2; ++i)
#pragma unroll
            for (int j = 0; j < 4; ++j)
#pragma unroll
                for (int l = 0; l < 16; ++l) acc[i][j][l] = 0.0f;

#pragma unroll
        for (int c = 0; c < 4; ++c) {
            // issue DMA for the NEXT chunk into the other buffer (that buffer's
            // readers finished before the barrier we just passed). Last phase
            // wraps to chunk 0 — harmless in-bounds re-read.
            {
                const int gn = ((kt << 2) + c + 1) & 255;
                dma_chunk(embed, (gn >> 2) << 6, gn & 3, w, L, &es2[((c & 1) ^ 1) << 12]);
            }
            const float* esc = &es2[(c & 1) << 12];
            // np.einsum outstride0_two: groups of 4 vectors nested REVERSED (a3..a0)
#pragma unroll
            for (int jj = 3; jj >= 0; --jj) {
#pragma unroll
                for (int q = 0; q < 4; ++q) {
                    const int dl = ((c * 4 + jj) << 4) + (q << 2);
                    const int dls = dl ^ xkey;
                    const int el = (jj << 4) + (q << 2);
                    const int els = el ^ eskey;
                    const float4 a0 = *reinterpret_cast<const float4*>(&xs[(tr << 8) + dls]);
                    const float4 a1 = *reinterpret_cast<const float4*>(&xs[((tr + 16) << 8) + dls]);
                    const int lb = q << 2;
#pragma unroll
                    for (int j2 = 0; j2 < 4; ++j2) {
                        const float4 b = *reinterpret_cast<const float4*>(&esc[((tc + 16 * j2) << 6) + els]);
                        acc[0][j2][lb + 0] = __builtin_fmaf(a0.x, b.x, acc[0][j2][lb + 0]);
                        acc[0][j2][lb + 1] = __builtin_fmaf(a0.y, b.y, acc[0][j2][lb + 1]);
                        acc[0][j2][lb + 2] = __builtin_fmaf(a0.z, b.z, acc[0][j2][lb + 2]);
                        acc[0][j2][lb + 3] = __builtin_fmaf(a0.w, b.w, acc[0][j2][lb + 3]);
                        acc[1][j2][lb + 0] = __builtin_fmaf(a1.x, b.x, acc[1][j2][lb + 0]);
                        acc[1][j2][lb + 1] = __builtin_fmaf(a1.y, b.y, acc[1][j2][lb + 1]);
                        acc[1][j2][lb + 2] = __builtin_fmaf(a1.z, b.z, acc[1][j2][lb + 2]);
                        acc[1][j2][lb + 3] = __builtin_fmaf(a1.w, b.w, acc[1][j2][lb + 3]);
                    }
                }
            }
            __syncthreads();  // compute done + this phase's DMA drained; next buffer ready
        }
#pragma unroll
        for (int j2 = 0; j2 < 4; ++j2) {
            const int kk = k0 + tc + 16 * j2;
            const float eq = esq[kk];
            {
                const float dot = hsum16_np(acc[0][j2]);
                const float dist = __fadd_rn(__fsub_rn(xq0, __fmul_rn(2.0f, dot)), eq);
                unsigned u = __float_as_uint(dist);
                u ^= (unsigned)((int)u >> 31) | 0x80000000u;
                const unsigned long long key = ((unsigned long long)u << 32) | (unsigned)kk;
                best0 = key < best0 ? key : best0;
            }
            {
                const float dot = hsum16_np(acc[1][j2]);
                const float dist = __fadd_rn(__fsub_rn(xq1, __fmul_rn(2.0f, dot)), eq);
                unsigned u = __float_as_uint(dist);
                u ^= (unsigned)((int)u >> 31) | 0x80000000u;
                const unsigned long long key = ((unsigned long long)u << 32) | (unsigned)kk;
                best1 = key < best1 ? key : best1;
            }
        }
    }

    // all waves passed the final phase barrier; xs no longer read -> alias as red
    red[tr * 16 + tc] = best0;
    red[(tr + 16) * 16 + tc] = best1;
    __syncthreads();
    if (tid < 32) {
        unsigned long long m = red[tid * 16];
#pragma unroll
        for (int t = 1; t < 16; ++t) {
            unsigned long long v = red[tid * 16 + t];
            m = v < m ? v : m;
        }
        out_idx[n0 + tid] = (int)(m & 0xFFFFFFFFu);
    }
}

__global__ void k_scatter(const float* __restrict__ x, const float* __restrict__ embed,
                          const int* __restrict__ idx, float* __restrict__ out,
                          float* __restrict__ loss_acc, float* __restrict__ bins,
                          float* __restrict__ esum, float* __restrict__ ind_out) {
    const int n = blockIdx.x;
    const int d = threadIdx.x;
    const int k = idx[n];
    const size_t xi = ((size_t)n << 8) + d;
    const float xv = x[xi];
    const float qv = embed[((size_t)k << 8) + d];
    const float diff = __fsub_rn(qv, xv);
    out[xi] = __fadd_rn(xv, diff);
    atomicAdd(&esum[((size_t)k << 8) + d], xv);
    __shared__ float sred[256];
    sred[d] = __fmul_rn(diff, diff);
    __syncthreads();
    for (int s = 128; s > 0; s >>= 1) {
        if (d < s) sred[d] += sred[d + s];
        __syncthreads();
    }
    if (d == 0) {
        atomicAdd(loss_acc, sred[0]);
        atomicAdd(&bins[k], 1.0f);
        ind_out[n] = (float)k;
    }
}

__global__ void k_cluster(const float* __restrict__ cs, const float* __restrict__ bins,
                          float* __restrict__ ncs_out, float* __restrict__ n_out) {
    __shared__ float sred[1024];
    const int t = threadIdx.x;
    float s = 0.0f;
    for (int k = t; k < KCODES; k += 1024) {
        const float ncs = __fadd_rn(__fmul_rn(cs[k], 0.1f), __fmul_rn(bins[k], 0.9f));
        ncs_out[k] = ncs;
        s += ncs;
    }
    sred[t] = s;
    __syncthreads();
    for (int w = 512; w > 0; w >>= 1) {
        if (t < w) sred[t] += sred[t + w];
        __syncthreads();
    }
    if (t == 0) n_out[0] = sred[0];
}

__global__ void k_norm(const float* __restrict__ ea, const float* __restrict__ esum,
                       const float* __restrict__ ncs, const float* __restrict__ nptr,
                       float* __restrict__ en_out) {
    const int i = blockIdx.x * 256 + threadIdx.x;
    const int k = i >> 8;
    const float n = nptr[0];
    const float ncsk = ncs[k];
    const float smoothed = (ncsk + 1e-5f) / (n + 4096.0f * 1e-5f) * n;
    const float nea = __fadd_rn(__fmul_rn(ea[i], 0.1f), __fmul_rn(esum[i], 0.9f));
    en_out[i] = nea / smoothed;
}

__global__ void k_loss(const float* __restrict__ acc, float* __restrict__ dst) {
    if (threadIdx.x == 0) dst[0] = acc[0] * (1.0f / 8388608.0f);
}

extern "C" void kernel_launch(void* const* d_in, const int* in_sizes, int n_in, void* d_out,
                              int out_size, void* d_ws, size_t ws_size, hipStream_t stream) {
    (void)in_sizes; (void)n_in; (void)out_size; (void)ws_size;
    const float* x = (const float*)d_in[0];
    const float* emb = (const float*)d_in[1];
    const float* cs = (const float*)d_in[2];
    const float* ea = (const float*)d_in[3];
    float* ws = (float*)d_ws;
    float* out = (float*)d_out;

    float* w_loss = ws + WS_LOSS;
    float* w_bins = ws + WS_BINS;
    float* w_esum = ws + WS_ESUM;
    float* w_n = ws + WS_N;
    float* w_xsq = ws + WS_XSQ;
    float* w_esq = ws + WS_ESQ;
    int* w_idx = (int*)(ws + WS_IDX);

    float* o_out = out;              // [N*D]
    float* o_loss = out + 8388608;   // [1]
    float* o_ind = out + 8388609;    // [N]
    float* o_ncs = out + 8421377;    // [K]
    float* o_en = out + 8425473;     // [K*D]

    // zero loss + bins + esum each call (deterministic across replays)
    hipMemsetAsync(d_ws, 0, (size_t)WS_N * sizeof(float), stream);

    k_rownorm<<<NROWS / 256, 256, 0, stream>>>(x, w_xsq, NROWS);
    k_rownorm<<<KCODES / 256, 256, 0, stream>>>(emb, w_esq, KCODES);
    k_argmin<<<NROWS / 32, 256, 0, stream>>>(x, emb, w_xsq, w_esq, w_idx);
    k_scatter<<<NROWS, 256, 0, stream>>>(x, emb, w_idx, o_out, w_loss, w_bins, w_esum, o_ind);
    k_cluster<<<1, 1024, 0, stream>>>(cs, w_bins, o_ncs, w_n);
    k_norm<<<(KCODES * DDIM) / 256, 256, 0, stream>>>(ea, w_esum, o_ncs, w_n, o_en);
    k_loss<<<1, 64, 0, stream>>>(w_loss, o_loss);
}

// Round 7
// 1778.114 us; speedup vs baseline: 1.4745x; 1.4745x over previous
//
#include <hip/hip_runtime.h>
#include <cstdint>
#include <cstddef>

#define NROWS 32768
#define DDIM 256
#define KCODES 4096

// ---------------- ws layout (float offsets) ----------------
#define WS_LOSS 0
#define WS_BINS 1
#define WS_ESUM (1 + KCODES)
#define WS_N (WS_ESUM + KCODES * DDIM)
#define WS_XSQ (WS_N + 1)
#define WS_ESQ (WS_XSQ + NROWS)
#define WS_IDX (WS_ESQ + KCODES)

// gcc _mm512_reduce_add_ps pairing tree (numpy npyv_sum_f32 on AVX512)
__device__ __forceinline__ float hsum16_np(const float a[16]) {
    float t3[8];
#pragma unroll
    for (int m = 0; m < 8; ++m) t3[m] = __fadd_rn(a[m + 8], a[m]);
    float t6[4];
#pragma unroll
    for (int m = 0; m < 4; ++m) t6[m] = __fadd_rn(t3[m + 4], t3[m]);
    return __fadd_rn(__fadd_rn(t6[0], t6[2]), __fadd_rn(t6[1], t6[3]));
}

// numpy FLOAT_pairwise_sum of squares, 128-element SIMD block (AVX512):
// 8 zmm loads, lane-wise tree ((v0+v1)+(v2+v3))+((v4+v5)+(v6+v7)), horizontal gcc tree
__device__ __forceinline__ float np_sum_sq_128(const float* a) {
    float t[16];
#pragma unroll
    for (int l = 0; l < 16; ++l) {
        float m0 = __fmul_rn(a[l], a[l]);
        float m1 = __fmul_rn(a[16 + l], a[16 + l]);
        float m2 = __fmul_rn(a[32 + l], a[32 + l]);
        float m3 = __fmul_rn(a[48 + l], a[48 + l]);
        float m4 = __fmul_rn(a[64 + l], a[64 + l]);
        float m5 = __fmul_rn(a[80 + l], a[80 + l]);
        float m6 = __fmul_rn(a[96 + l], a[96 + l]);
        float m7 = __fmul_rn(a[112 + l], a[112 + l]);
        float s01 = __fadd_rn(m0, m1);
        float s23 = __fadd_rn(m2, m3);
        float s45 = __fadd_rn(m4, m5);
        float s67 = __fadd_rn(m6, m7);
        t[l] = __fadd_rn(__fadd_rn(s01, s23), __fadd_rn(s45, s67));
    }
    return hsum16_np(t);
}

__global__ void k_rownorm(const float* __restrict__ src, float* __restrict__ dst, int rows) {
    int r = blockIdx.x * blockDim.x + threadIdx.x;
    if (r < rows) {
        const float* p = src + ((size_t)r << 8);
        // numpy pairwise recursion: 256 -> 128 + 128
        dst[r] = __fadd_rn(np_sum_sq_128(p), np_sum_sq_128(p + 128));
    }
}

// fused dist + argmin. block tile: 32 rows x 64 cols, 512 threads, micro 2x2,
// 16 lane-accumulators per pair (mimics np.einsum single-vaccum FMA chain).
//
// Occupancy history (256-thread era):
//   launch_bounds(256,2): VGPR capped 128 -> acc (128 regs) spills, 607MB wr.
//   launch_bounds(256,1): no spill (116 VGPR) but 1 block/CU -> regressed.
//   waves_per_eu(2):      2 blocks/CU, 116 VGPR, 1388us, VALUBusy 48%.
//   reg-prefetch / (2,2) / global_load_lds DMA (R3-R5): every variant that
//     raised pressure past ~116 got spilled to the 128 bucket by the
//     allocator (scratch or LDS spill, 1.4-100 GB traffic). Unlandable.
// R6: make working set agree with the natural 128-VGPR bucket instead:
// 512 threads, 4 pairs/thread -> acc[2][2][16]=64 regs (~105 total). LDS
// unchanged (50688B) -> 2 blocks/CU = 16 waves/CU = 4 waves/SIMD (2x R2's
// TLP; R2 was latency-bound: FMA floor ~1.05M cyc/SIMD vs 2.9M observed).
// Waves col-split (waves 0-3: cols 0-31, 4-7: cols 32-63) so es LDS dup
// stays at R2's level (4-lane broadcast per es read preserved).
__global__ __attribute__((amdgpu_flat_work_group_size(512, 512), amdgpu_waves_per_eu(4)))
void k_argmin(const float* __restrict__ x,
              const float* __restrict__ embed,
              const float* __restrict__ xsq,
              const float* __restrict__ esq,
              int* __restrict__ out_idx) {
    __shared__ float xs[32][260];  // full D staged once, pad keeps b128 ~2-way
    __shared__ float es[64][68];   // one 64-d chunk of the e-tile; reused as red buffer
    unsigned long long* red = (unsigned long long*)&es[0][0];  // 32*32*8B = 8KB <= 17KB

    const int tid = threadIdx.x;
    const int lane = tid & 63;
    const int w = tid >> 6;
    const int g = w >> 2;                          // col group: 0 -> cols 0-31, 1 -> 32-63
    const int tc = lane & 15;
    const int tr = ((w & 3) << 2) + (lane >> 4);   // 0..15
    const int cbase = (g << 5) + tc;               // thread's col pair: cbase, cbase+16
    const int n0 = blockIdx.x * 32;

#pragma unroll
    for (int p = 0; p < 4; ++p) {
        int v = tid + p * 512;
        int r = v >> 6;
        int c4 = (v & 63) << 2;
        const float4 f = *reinterpret_cast<const float4*>(x + ((size_t)(n0 + r) << 8) + c4);
        *reinterpret_cast<float4*>(&xs[r][c4]) = f;
    }

    const float xq0 = xsq[n0 + tr];
    const float xq1 = xsq[n0 + tr + 16];

    unsigned long long best0 = ~0ull, best1 = ~0ull;

    for (int kt = 0; kt < KCODES / 64; ++kt) {
        const int k0 = kt * 64;
        float acc[2][2][16];
#pragma unroll
        for (int i = 0; i < 2; ++i)
#pragma unroll
            for (int j = 0; j < 2; ++j)
#pragma unroll
                for (int l = 0; l < 16; ++l) acc[i][j][l] = 0.0f;

        for (int c = 0; c < 4; ++c) {
            __syncthreads();
#pragma unroll
            for (int p = 0; p < 2; ++p) {
                int v = tid + p * 512;
                int r = v >> 4;
                int c4 = (v & 15) << 2;
                const float4 f = *reinterpret_cast<const float4*>(
                    embed + ((size_t)(k0 + r) << 8) + (c << 6) + c4);
                *reinterpret_cast<float4*>(&es[r][c4]) = f;
            }
            __syncthreads();
            // np.einsum outstride0_two: groups of 4 vectors nested REVERSED (a3..a0)
#pragma unroll
            for (int jj = 3; jj >= 0; --jj) {
#pragma unroll
                for (int q = 0; q < 4; ++q) {
                    const int dl = ((c * 4 + jj) << 4) + (q << 2);
                    const int el = (jj << 4) + (q << 2);
                    const float4 a0 = *reinterpret_cast<const float4*>(&xs[tr][dl]);
                    const float4 a1 = *reinterpret_cast<const float4*>(&xs[tr + 16][dl]);
                    const int lb = q << 2;
#pragma unroll
                    for (int j2 = 0; j2 < 2; ++j2) {
                        const float4 b = *reinterpret_cast<const float4*>(&es[cbase + 16 * j2][el]);
                        acc[0][j2][lb + 0] = __builtin_fmaf(a0.x, b.x, acc[0][j2][lb + 0]);
                        acc[0][j2][lb + 1] = __builtin_fmaf(a0.y, b.y, acc[0][j2][lb + 1]);
                        acc[0][j2][lb + 2] = __builtin_fmaf(a0.z, b.z, acc[0][j2][lb + 2]);
                        acc[0][j2][lb + 3] = __builtin_fmaf(a0.w, b.w, acc[0][j2][lb + 3]);
                        acc[1][j2][lb + 0] = __builtin_fmaf(a1.x, b.x, acc[1][j2][lb + 0]);
                        acc[1][j2][lb + 1] = __builtin_fmaf(a1.y, b.y, acc[1][j2][lb + 1]);
                        acc[1][j2][lb + 2] = __builtin_fmaf(a1.z, b.z, acc[1][j2][lb + 2]);
                        acc[1][j2][lb + 3] = __builtin_fmaf(a1.w, b.w, acc[1][j2][lb + 3]);
                    }
                }
            }
        }
#pragma unroll
        for (int j2 = 0; j2 < 2; ++j2) {
            const int kk = k0 + cbase + 16 * j2;
            const float eq = esq[kk];
            {
                const float dot = hsum16_np(acc[0][j2]);
                const float dist = __fadd_rn(__fsub_rn(xq0, __fmul_rn(2.0f, dot)), eq);
                unsigned u = __float_as_uint(dist);
                u ^= (unsigned)((int)u >> 31) | 0x80000000u;
                const unsigned long long key = ((unsigned long long)u << 32) | (unsigned)kk;
                best0 = key < best0 ? key : best0;
            }
            {
                const float dot = hsum16_np(acc[1][j2]);
                const float dist = __fadd_rn(__fsub_rn(xq1, __fmul_rn(2.0f, dot)), eq);
                unsigned u = __float_as_uint(dist);
                u ^= (unsigned)((int)u >> 31) | 0x80000000u;
                const unsigned long long key = ((unsigned long long)u << 32) | (unsigned)kk;
                best1 = key < best1 ? key : best1;
            }
        }
    }

    __syncthreads();  // all es reads done before aliasing as red
    red[tr * 32 + (g << 4) + tc] = best0;
    red[(tr + 16) * 32 + (g << 4) + tc] = best1;
    __syncthreads();
    if (tid < 32) {
        unsigned long long m = red[tid * 32];
#pragma unroll
        for (int t = 1; t < 32; ++t) {
            unsigned long long v = red[tid * 32 + t];
            m = v < m ? v : m;
        }
        out_idx[n0 + tid] = (int)(m & 0xFFFFFFFFu);
    }
}

__global__ void k_scatter(const float* __restrict__ x, const float* __restrict__ embed,
                          const int* __restrict__ idx, float* __restrict__ out,
                          float* __restrict__ loss_acc, float* __restrict__ bins,
                          float* __restrict__ esum, float* __restrict__ ind_out) {
    const int n = blockIdx.x;
    const int d = threadIdx.x;
    const int k = idx[n];
    const size_t xi = ((size_t)n << 8) + d;
    const float xv = x[xi];
    const float qv = embed[((size_t)k << 8) + d];
    const float diff = __fsub_rn(qv, xv);
    out[xi] = __fadd_rn(xv, diff);
    atomicAdd(&esum[((size_t)k << 8) + d], xv);
    __shared__ float sred[256];
    sred[d] = __fmul_rn(diff, diff);
    __syncthreads();
    for (int s = 128; s > 0; s >>= 1) {
        if (d < s) sred[d] += sred[d + s];
        __syncthreads();
    }
    if (d == 0) {
        atomicAdd(loss_acc, sred[0]);
        atomicAdd(&bins[k], 1.0f);
        ind_out[n] = (float)k;
    }
}

__global__ void k_cluster(const float* __restrict__ cs, const float* __restrict__ bins,
                          float* __restrict__ ncs_out, float* __restrict__ n_out) {
    __shared__ float sred[1024];
    const int t = threadIdx.x;
    float s = 0.0f;
    for (int k = t; k < KCODES; k += 1024) {
        const float ncs = __fadd_rn(__fmul_rn(cs[k], 0.1f), __fmul_rn(bins[k], 0.9f));
        ncs_out[k] = ncs;
        s += ncs;
    }
    sred[t] = s;
    __syncthreads();
    for (int w = 512; w > 0; w >>= 1) {
        if (t < w) sred[t] += sred[t + w];
        __syncthreads();
    }
    if (t == 0) n_out[0] = sred[0];
}

__global__ void k_norm(const float* __restrict__ ea, const float* __restrict__ esum,
                       const float* __restrict__ ncs, const float* __restrict__ nptr,
                       float* __restrict__ en_out) {
    const int i = blockIdx.x * 256 + threadIdx.x;
    const int k = i >> 8;
    const float n = nptr[0];
    const float ncsk = ncs[k];
    const float smoothed = (ncsk + 1e-5f) / (n + 4096.0f * 1e-5f) * n;
    const float nea = __fadd_rn(__fmul_rn(ea[i], 0.1f), __fmul_rn(esum[i], 0.9f));
    en_out[i] = nea / smoothed;
}

__global__ void k_loss(const float* __restrict__ acc, float* __restrict__ dst) {
    if (threadIdx.x == 0) dst[0] = acc[0] * (1.0f / 8388608.0f);
}

extern "C" void kernel_launch(void* const* d_in, const int* in_sizes, int n_in, void* d_out,
                              int out_size, void* d_ws, size_t ws_size, hipStream_t stream) {
    (void)in_sizes; (void)n_in; (void)out_size; (void)ws_size;
    const float* x = (const float*)d_in[0];
    const float* emb = (const float*)d_in[1];
    const float* cs = (const float*)d_in[2];
    const float* ea = (const float*)d_in[3];
    float* ws = (float*)d_ws;
    float* out = (float*)d_out;

    float* w_loss = ws + WS_LOSS;
    float* w_bins = ws + WS_BINS;
    float* w_esum = ws + WS_ESUM;
    float* w_n = ws + WS_N;
    float* w_xsq = ws + WS_XSQ;
    float* w_esq = ws + WS_ESQ;
    int* w_idx = (int*)(ws + WS_IDX);

    float* o_out = out;              // [N*D]
    float* o_loss = out + 8388608;   // [1]
    float* o_ind = out + 8388609;    // [N]
    float* o_ncs = out + 8421377;    // [K]
    float* o_en = out + 8425473;     // [K*D]

    // zero loss + bins + esum each call (deterministic across replays)
    hipMemsetAsync(d_ws, 0, (size_t)WS_N * sizeof(float), stream);

    k_rownorm<<<NROWS / 256, 256, 0, stream>>>(x, w_xsq, NROWS);
    k_rownorm<<<KCODES / 256, 256, 0, stream>>>(emb, w_esq, KCODES);
    k_argmin<<<NROWS / 32, 512, 0, stream>>>(x, emb, w_xsq, w_esq, w_idx);
    k_scatter<<<NROWS, 256, 0, stream>>>(x, emb, w_idx, o_out, w_loss, w_bins, w_esum, o_ind);
    k_cluster<<<1, 1024, 0, stream>>>(cs, w_bins, o_ncs, w_n);
    k_norm<<<(KCODES * DDIM) / 256, 256, 0, stream>>>(ea, w_esum, o_ncs, w_n, o_en);
    k_loss<<<1, 64, 0, stream>>>(w_loss, o_loss);
}

// Round 8
// 837.266 us; speedup vs baseline: 3.1313x; 2.1237x over previous
//
#include <hip/hip_runtime.h>
#include <hip/hip_bf16.h>
#include <cstdint>
#include <cstddef>

#define NROWS 32768
#define DDIM 256
#define KCODES 4096

typedef __attribute__((ext_vector_type(8))) short s16x8;
typedef __attribute__((ext_vector_type(4))) float f32x4;
typedef unsigned long long u64;
typedef unsigned int u32;

// ---------------- ws layout (float offsets), all 16B-aligned blocks ----------
#define WS_LOSS 0
#define WS_CNT 1
#define WS_EMAX 2
#define WS_DISTRUST 3
#define WS_NSC 4
#define WS_BINS 8
#define WS_ESUM 4104
#define WS_XSQ 1052680
#define WS_ESQ 1085448
#define WS_IDX 1089544
#define WS_KEY 1122312                 // u64[32768]
#define WS_TKEY 1187848                // u64[8*32768]
#define WS_TM2 1712136                 // f32[8*32768]
#define WS_LIST 1974280                // u32[32768]
#define WS_EH 2007048                  // ushort[1048576]
#define WS_EL 2531336                  // ushort[1048576]
#define WS_TOTAL 3055624
#define WS_ZERO_FLOATS 1052680         // loss..esum (incl cnt/distrust/nsc)

__device__ __forceinline__ float hsum16_np(const float a[16]) {
    float t3[8];
#pragma unroll
    for (int m = 0; m < 8; ++m) t3[m] = __fadd_rn(a[m + 8], a[m]);
    float t6[4];
#pragma unroll
    for (int m = 0; m < 4; ++m) t6[m] = __fadd_rn(t3[m + 4], t3[m]);
    return __fadd_rn(__fadd_rn(t6[0], t6[2]), __fadd_rn(t6[1], t6[3]));
}

__device__ __forceinline__ float np_sum_sq_128(const float* a) {
    float t[16];
#pragma unroll
    for (int l = 0; l < 16; ++l) {
        float m0 = __fmul_rn(a[l], a[l]);
        float m1 = __fmul_rn(a[16 + l], a[16 + l]);
        float m2 = __fmul_rn(a[32 + l], a[32 + l]);
        float m3 = __fmul_rn(a[48 + l], a[48 + l]);
        float m4 = __fmul_rn(a[64 + l], a[64 + l]);
        float m5 = __fmul_rn(a[80 + l], a[80 + l]);
        float m6 = __fmul_rn(a[96 + l], a[96 + l]);
        float m7 = __fmul_rn(a[112 + l], a[112 + l]);
        float s01 = __fadd_rn(m0, m1);
        float s23 = __fadd_rn(m2, m3);
        float s45 = __fadd_rn(m4, m5);
        float s67 = __fadd_rn(m6, m7);
        t[l] = __fadd_rn(__fadd_rn(s01, s23), __fadd_rn(s45, s67));
    }
    return hsum16_np(t);
}

__global__ void k_rownorm(const float* __restrict__ src, float* __restrict__ dst, int rows) {
    int r = blockIdx.x * blockDim.x + threadIdx.x;
    if (r < rows) {
        const float* p = src + ((size_t)r << 8);
        dst[r] = __fadd_rn(np_sum_sq_128(p), np_sum_sq_128(p + 128));
    }
}

__global__ void k_emax(const float* __restrict__ esq, float* __restrict__ emax) {
    __shared__ float s[1024];
    int t = threadIdx.x;
    float m = 0.0f;
    for (int i = t; i < KCODES; i += 1024) m = fmaxf(m, esq[i]);
    s[t] = m;
    __syncthreads();
    for (int w = 512; w > 0; w >>= 1) {
        if (t < w) s[t] = fmaxf(s[t], s[t + w]);
        __syncthreads();
    }
    if (t == 0) emax[0] = s[0];
}

// RNE bf16 from fp32 bits (normal values only here)
__device__ __forceinline__ ushort bf16_rn(float x) {
    u32 u = __float_as_uint(x);
    u32 r = (u + 0x7fffu + ((u >> 16) & 1u)) >> 16;
    return (ushort)r;
}
__device__ __forceinline__ float bf16_f(ushort h) { return __uint_as_float(((u32)h) << 16); }

__global__ void k_pack(const float* __restrict__ src, ushort* __restrict__ hi,
                       ushort* __restrict__ lo) {
    int i = (blockIdx.x * 256 + threadIdx.x) * 8;
    float4 v0 = *reinterpret_cast<const float4*>(src + i);
    float4 v1 = *reinterpret_cast<const float4*>(src + i + 4);
    float f[8] = {v0.x, v0.y, v0.z, v0.w, v1.x, v1.y, v1.z, v1.w};
    ushort h[8], l[8];
#pragma unroll
    for (int j = 0; j < 8; ++j) {
        h[j] = bf16_rn(f[j]);
        l[j] = bf16_rn(__fsub_rn(f[j], bf16_f(h[j])));
    }
    *reinterpret_cast<s16x8*>(hi + i) = *reinterpret_cast<s16x8*>(h);
    *reinterpret_cast<s16x8*>(lo + i) = *reinterpret_cast<s16x8*>(l);
}

__device__ __forceinline__ float keyval_(u64 k) {
    u32 u = (u32)(k >> 32);
    u = (u & 0x80000000u) ? (u ^ 0x80000000u) : ~u;
    return __uint_as_float(u);
}
__device__ __forceinline__ u64 packkey(float d, u32 j) {
    u32 u = __float_as_uint(d);
    u ^= (u32)((int)u >> 31) | 0x80000000u;
    return ((u64)u << 32) | j;
}
#define KEY_INIT 0xFF8000007FFFFFFFull  // packkey(+INF, 0x7fffffff)

__device__ __forceinline__ void dma16(const void* g, void* l) {
    __builtin_amdgcn_global_load_lds(
        (const __attribute__((address_space(1))) void*)g,
        (__attribute__((address_space(3))) void*)l, 16, 0, 0);
}

// Approx distances via bf16-split MFMA. Block: 256 thr (4 waves), tile 128n x 512j
// (8 Jsteps of 64), D in 4 chunks of 64. Wave: 32n x 64j, acc[2][4] f32x4.
// LDS 48KB unpadded + row-XOR swizzle (key=(row&7)<<4 bytes), DMA source pre-swizzled.
// s~ = xh*eh + xh*el + xl*eh accumulated into one acc (error bound covers any order,
// incl. unknown MFMA-internal k permutation: A and B share the lane k-mapping).
__global__ __attribute__((amdgpu_flat_work_group_size(256, 256), amdgpu_waves_per_eu(3, 3)))
void k_mfma(const ushort* __restrict__ xh_g, const ushort* __restrict__ xl_g,
            const ushort* __restrict__ eh_g, const ushort* __restrict__ el_g,
            const float* __restrict__ xsq, const float* __restrict__ esq,
            u64* __restrict__ tkey, float* __restrict__ tm2) {
    __shared__ __align__(16) ushort xh_s[8192];  // [128][64]
    __shared__ __align__(16) ushort xl_s[8192];
    __shared__ __align__(16) ushort eh_s[4096];  // [64][64]
    __shared__ __align__(16) ushort el_s[4096];

    const int tid = threadIdx.x;
    const int w = tid >> 6, l = tid & 63, lr = l & 15, lg = l >> 4;
    const int n0 = blockIdx.x * 128, jb = blockIdx.y, j0 = jb * 512;
    const int key = (lr & 7) << 4;

    float xq[8];
#pragma unroll
    for (int i = 0; i < 8; ++i)
        xq[i] = xsq[n0 + w * 32 + (i >> 2) * 16 + lg * 4 + (i & 3)];

    u64 K1[8];
    float M2[8];
#pragma unroll
    for (int i = 0; i < 8; ++i) { K1[i] = KEY_INIT; M2[i] = __uint_as_float(0x7F800000u); }

    for (int js = 0; js < 8; ++js) {
        const int jbase = j0 + js * 64;
        f32x4 acc[2][4];
#pragma unroll
        for (int a = 0; a < 2; ++a)
#pragma unroll
            for (int b = 0; b < 4; ++b) acc[a][b] = (f32x4){0.f, 0.f, 0.f, 0.f};

        for (int c = 0; c < 4; ++c) {
            __syncthreads();  // prior phase's reads done
#pragma unroll
            for (int p = 0; p < 4; ++p) {
                int m = tid + p * 256, r = m >> 3, cb = (m & 7) << 4;
                int so = (n0 + r) * 256 + c * 64 + ((cb ^ ((r & 7) << 4)) >> 1);
                dma16(xh_g + so, (char*)xh_s + m * 16);
                dma16(xl_g + so, (char*)xl_s + m * 16);
            }
#pragma unroll
            for (int p = 0; p < 2; ++p) {
                int m = tid + p * 256, r = m >> 3, cb = (m & 7) << 4;
                int so = (jbase + r) * 256 + c * 64 + ((cb ^ ((r & 7) << 4)) >> 1);
                dma16(eh_g + so, (char*)eh_s + m * 16);
                dma16(el_g + so, (char*)el_s + m * 16);
            }
            __syncthreads();  // DMA drained (vmcnt0 before barrier)
#pragma unroll
            for (int ks = 0; ks < 2; ++ks) {
                const int off = (ks * 64 + lg * 16) ^ key;
                s16x8 axh[2], axl[2];
#pragma unroll
                for (int ns = 0; ns < 2; ++ns) {
                    const int row = w * 32 + ns * 16 + lr;
                    axh[ns] = *(const s16x8*)((const char*)(xh_s + row * 64) + off);
                    axl[ns] = *(const s16x8*)((const char*)(xl_s + row * 64) + off);
                }
#pragma unroll
                for (int jp = 0; jp < 2; ++jp) {
                    s16x8 beh[2], bel[2];
#pragma unroll
                    for (int q = 0; q < 2; ++q) {
                        const int row = (jp * 2 + q) * 16 + lr;
                        beh[q] = *(const s16x8*)((const char*)(eh_s + row * 64) + off);
                        bel[q] = *(const s16x8*)((const char*)(el_s + row * 64) + off);
                    }
#pragma unroll
                    for (int q = 0; q < 2; ++q) {
                        const int jsub = jp * 2 + q;
#pragma unroll
                        for (int ns = 0; ns < 2; ++ns) {
                            acc[ns][jsub] = __builtin_amdgcn_mfma_f32_16x16x32_bf16(
                                axh[ns], beh[q], acc[ns][jsub], 0, 0, 0);
                            acc[ns][jsub] = __builtin_amdgcn_mfma_f32_16x16x32_bf16(
                                axh[ns], bel[q], acc[ns][jsub], 0, 0, 0);
                            acc[ns][jsub] = __builtin_amdgcn_mfma_f32_16x16x32_bf16(
                                axl[ns], beh[q], acc[ns][jsub], 0, 0, 0);
                        }
                    }
                }
            }
        }
        // epilogue for this Jstep: d~ with the exact final-op sequence
#pragma unroll
        for (int jsub = 0; jsub < 4; ++jsub) {
            const int j = jbase + jsub * 16 + lr;
            const float eq = esq[j];
#pragma unroll
            for (int ns = 0; ns < 2; ++ns)
#pragma unroll
                for (int r = 0; r < 4; ++r) {
                    const float s = acc[ns][jsub][r];
                    const float d = __fadd_rn(__fsub_rn(xq[ns * 4 + r], __fmul_rn(2.0f, s)), eq);
                    const u64 kk = packkey(d, (u32)j);
                    const int i8 = ns * 4 + r;
                    if (kk < K1[i8]) { M2[i8] = keyval_(K1[i8]); K1[i8] = kk; }
                    else if (d < M2[i8]) M2[i8] = d;
                }
        }
    }
    // cross-lane merge over the 16 j-lanes (masks stay in-group)
#pragma unroll
    for (int i8 = 0; i8 < 8; ++i8) {
        u64 k1 = K1[i8];
        float m2 = M2[i8];
#pragma unroll
        for (int mk = 1; mk < 16; mk <<= 1) {
            u32 klo = __shfl_xor((u32)k1, mk);
            u32 khi = __shfl_xor((u32)(k1 >> 32), mk);
            float om2 = __shfl_xor(m2, mk);
            u64 ok = ((u64)khi << 32) | klo;
            if (ok < k1) { m2 = fminf(om2, keyval_(k1)); k1 = ok; }
            else m2 = fminf(m2, keyval_(ok));
        }
        if (lr == 0) {
            const int n = n0 + w * 32 + (i8 >> 2) * 16 + lg * 4 + (i8 & 3);
            tkey[(size_t)jb * NROWS + n] = k1;
            tm2[(size_t)jb * NROWS + n] = m2;
        }
    }
}

__global__ void k_merge(const u64* __restrict__ tkey, const float* __restrict__ tm2,
                        const float* __restrict__ xsq, const float* __restrict__ emaxp,
                        u64* __restrict__ key64, u32* __restrict__ list, u32* __restrict__ cnt) {
    const int n = blockIdx.x * 256 + threadIdx.x;
    u64 k1 = tkey[n];
    float m2 = tm2[n];
#pragma unroll
    for (int jb = 1; jb < 8; ++jb) {
        u64 ok = tkey[(size_t)jb * NROWS + n];
        float om2 = tm2[(size_t)jb * NROWS + n];
        if (ok < k1) { m2 = fminf(om2, keyval_(k1)); k1 = ok; }
        else m2 = fminf(m2, keyval_(ok));
    }
    const float B = sqrtf(xsq[n] * emaxp[0]);
    const float Ed = 2.4e-4f * B + 1.5e-4f;
    if (m2 - keyval_(k1) <= 2.0f * Ed) {
        key64[n] = ~0ull;
        list[atomicAdd(cnt, 1u)] = (u32)n;
    } else {
        key64[n] = k1;
    }
}

// exact numpy-order dist(n, approx-winner) vs d~(winner): bound-slip / layout guard
__global__ void k_verify(const float* __restrict__ x, const float* __restrict__ e,
                         const float* __restrict__ xsq, const float* __restrict__ esq,
                         const float* __restrict__ emaxp, u64* __restrict__ key64,
                         u32* __restrict__ list, u32* __restrict__ cnt,
                         u32* __restrict__ distrust) {
    const int li = threadIdx.x & 15;
    const int n = blockIdx.x * 16 + (threadIdx.x >> 4);
    const u64 k = key64[n];
    const bool active = (k != ~0ull);
    const int idx = active ? (int)(k & 0xFFFu) : 0;
    const float* xr = x + ((size_t)n << 8);
    const float* er = e + ((size_t)idx << 8);
    float a = 0.0f;
    // lane-acc chain, block order b = {3,2,1,0,7,6,5,4,11,10,9,8,15,14,13,12}
#pragma unroll
    for (int g = 0; g < 4; ++g)
#pragma unroll
        for (int bb = 3; bb >= 0; --bb) {
            const int d = (g * 4 + bb) * 16 + li;
            a = __builtin_fmaf(xr[d], er[d], a);
        }
    const float s1 = __fadd_rn(__shfl_xor(a, 8), a);
    const float s2 = __fadd_rn(__shfl_xor(s1, 4), s1);
    const float u = __fadd_rn(s2, __shfl_xor(s2, 2));
    const float dot = __fadd_rn(u, __shfl_xor(u, 1));
    if (li == 0 && active) {
        const float d = __fadd_rn(__fsub_rn(xsq[n], __fmul_rn(2.0f, dot)), esq[idx]);
        const float dref = keyval_(k);
        const float B = sqrtf(xsq[n] * emaxp[0]);
        const float Ed = 2.4e-4f * B + 1.5e-4f;
        const float diff = fabsf(d - dref);
        if (diff > Ed) {
            key64[n] = ~0ull;
            list[atomicAdd(cnt, 1u)] = (u32)n;
            if (diff > 0.05f) atomicOr(distrust, 1u);
        }
    }
}

__global__ void k_distrust(const u32* __restrict__ distrust, u64* __restrict__ key64,
                           u32* __restrict__ list, u32* __restrict__ cnt) {
    if (*distrust == 0u) return;
    const int n = blockIdx.x * 256 + threadIdx.x;
    key64[n] = ~0ull;
    list[n] = (u32)n;
    if (n == 0) *cnt = (u32)NROWS;
}

// exact numpy-order argmin over a 512-k segment for 32 flagged rows (R6 inner)
__global__ __attribute__((amdgpu_flat_work_group_size(512, 512), amdgpu_waves_per_eu(4)))
void k_exact(const float* __restrict__ x, const float* __restrict__ embed,
             const float* __restrict__ xsq, const float* __restrict__ esq,
             const u32* __restrict__ list, const u32* __restrict__ cntp,
             u64* __restrict__ key64) {
    const u32 cnt = *cntp;
    const int grp = blockIdx.x >> 3, seg = blockIdx.x & 7;
    const u32 base = (u32)grp * 32u;
    if (base >= cnt) return;

    __shared__ float xs[32][260];
    __shared__ float es[64][68];
    u64* red = (u64*)&es[0][0];

    const int tid = threadIdx.x;
    const int lane = tid & 63;
    const int w = tid >> 6;
    const int g = w >> 2;
    const int tc = lane & 15;
    const int tr = ((w & 3) << 2) + (lane >> 4);
    const int cbase = (g << 5) + tc;

#pragma unroll
    for (int p = 0; p < 4; ++p) {
        int v = tid + p * 512;
        int r = v >> 6;
        int c4 = (v & 63) << 2;
        u32 row = list[(base + (u32)r < cnt) ? base + r : base];
        const float4 f = *reinterpret_cast<const float4*>(x + ((size_t)row << 8) + c4);
        *reinterpret_cast<float4*>(&xs[r][c4]) = f;
    }

    const u32 row0 = list[(base + (u32)tr < cnt) ? base + tr : base];
    const u32 row1 = list[(base + (u32)tr + 16u < cnt) ? base + tr + 16 : base];
    const float xq0 = xsq[row0];
    const float xq1 = xsq[row1];

    u64 best0 = ~0ull, best1 = ~0ull;

    for (int ktl = 0; ktl < 8; ++ktl) {
        const int k0 = seg * 512 + ktl * 64;
        float acc[2][2][16];
#pragma unroll
        for (int i = 0; i < 2; ++i)
#pragma unroll
            for (int j = 0; j < 2; ++j)
#pragma unroll
                for (int q = 0; q < 16; ++q) acc[i][j][q] = 0.0f;

        for (int c = 0; c < 4; ++c) {
            __syncthreads();
#pragma unroll
            for (int p = 0; p < 2; ++p) {
                int v = tid + p * 512;
                int r = v >> 4;
                int c4 = (v & 15) << 2;
                const float4 f = *reinterpret_cast<const float4*>(
                    embed + ((size_t)(k0 + r) << 8) + (c << 6) + c4);
                *reinterpret_cast<float4*>(&es[r][c4]) = f;
            }
            __syncthreads();
#pragma unroll
            for (int jj = 3; jj >= 0; --jj) {
#pragma unroll
                for (int q = 0; q < 4; ++q) {
                    const int dl = ((c * 4 + jj) << 4) + (q << 2);
                    const int el = (jj << 4) + (q << 2);
                    const float4 a0 = *reinterpret_cast<const float4*>(&xs[tr][dl]);
                    const float4 a1 = *reinterpret_cast<const float4*>(&xs[tr + 16][dl]);
                    const int lb = q << 2;
#pragma unroll
                    for (int j2 = 0; j2 < 2; ++j2) {
                        const float4 b = *reinterpret_cast<const float4*>(&es[cbase + 16 * j2][el]);
                        acc[0][j2][lb + 0] = __builtin_fmaf(a0.x, b.x, acc[0][j2][lb + 0]);
                        acc[0][j2][lb + 1] = __builtin_fmaf(a0.y, b.y, acc[0][j2][lb + 1]);
                        acc[0][j2][lb + 2] = __builtin_fmaf(a0.z, b.z, acc[0][j2][lb + 2]);
                        acc[0][j2][lb + 3] = __builtin_fmaf(a0.w, b.w, acc[0][j2][lb + 3]);
                        acc[1][j2][lb + 0] = __builtin_fmaf(a1.x, b.x, acc[1][j2][lb + 0]);
                        acc[1][j2][lb + 1] = __builtin_fmaf(a1.y, b.y, acc[1][j2][lb + 1]);
                        acc[1][j2][lb + 2] = __builtin_fmaf(a1.z, b.z, acc[1][j2][lb + 2]);
                        acc[1][j2][lb + 3] = __builtin_fmaf(a1.w, b.w, acc[1][j2][lb + 3]);
                    }
                }
            }
        }
#pragma unroll
        for (int j2 = 0; j2 < 2; ++j2) {
            const int kk = k0 + cbase + 16 * j2;
            const float eq = esq[kk];
            {
                const float dist = __fadd_rn(__fsub_rn(xq0, __fmul_rn(2.0f, hsum16_np(acc[0][j2]))), eq);
                const u64 kkey = packkey(dist, (u32)kk);
                best0 = kkey < best0 ? kkey : best0;
            }
            {
                const float dist = __fadd_rn(__fsub_rn(xq1, __fmul_rn(2.0f, hsum16_np(acc[1][j2]))), eq);
                const u64 kkey = packkey(dist, (u32)kk);
                best1 = kkey < best1 ? kkey : best1;
            }
        }
    }

    __syncthreads();
    red[tr * 32 + (g << 4) + tc] = best0;
    red[(tr + 16) * 32 + (g << 4) + tc] = best1;
    __syncthreads();
    if (tid < 32) {
        u64 m = red[tid * 32];
#pragma unroll
        for (int t = 1; t < 32; ++t) {
            u64 v = red[tid * 32 + t];
            m = v < m ? v : m;
        }
        if (base + (u32)tid < cnt) atomicMin(&key64[list[base + tid]], m);
    }
}

__global__ void k_finalize(const u64* __restrict__ key64, int* __restrict__ idx) {
    const int n = blockIdx.x * 256 + threadIdx.x;
    idx[n] = (int)(key64[n] & 0xFFFull);  // clamp-safe: j < 4096
}

// ---------- fallback full-exact argmin (R6 kernel, known-good 1432us) ----------
__global__ __attribute__((amdgpu_flat_work_group_size(512, 512), amdgpu_waves_per_eu(4)))
void k_argmin_full(const float* __restrict__ x, const float* __restrict__ embed,
                   const float* __restrict__ xsq, const float* __restrict__ esq,
                   int* __restrict__ out_idx) {
    __shared__ float xs[32][260];
    __shared__ float es[64][68];
    u64* red = (u64*)&es[0][0];
    const int tid = threadIdx.x;
    const int lane = tid & 63;
    const int w = tid >> 6;
    const int g = w >> 2;
    const int tc = lane & 15;
    const int tr = ((w & 3) << 2) + (lane >> 4);
    const int cbase = (g << 5) + tc;
    const int n0 = blockIdx.x * 32;
#pragma unroll
    for (int p = 0; p < 4; ++p) {
        int v = tid + p * 512;
        int r = v >> 6;
        int c4 = (v & 63) << 2;
        const float4 f = *reinterpret_cast<const float4*>(x + ((size_t)(n0 + r) << 8) + c4);
        *reinterpret_cast<float4*>(&xs[r][c4]) = f;
    }
    const float xq0 = xsq[n0 + tr];
    const float xq1 = xsq[n0 + tr + 16];
    u64 best0 = ~0ull, best1 = ~0ull;
    for (int kt = 0; kt < KCODES / 64; ++kt) {
        const int k0 = kt * 64;
        float acc[2][2][16];
#pragma unroll
        for (int i = 0; i < 2; ++i)
#pragma unroll
            for (int j = 0; j < 2; ++j)
#pragma unroll
                for (int q = 0; q < 16; ++q) acc[i][j][q] = 0.0f;
        for (int c = 0; c < 4; ++c) {
            __syncthreads();
#pragma unroll
            for (int p = 0; p < 2; ++p) {
                int v = tid + p * 512;
                int r = v >> 4;
                int c4 = (v & 15) << 2;
                const float4 f = *reinterpret_cast<const float4*>(
                    embed + ((size_t)(k0 + r) << 8) + (c << 6) + c4);
                *reinterpret_cast<float4*>(&es[r][c4]) = f;
            }
            __syncthreads();
#pragma unroll
            for (int jj = 3; jj >= 0; --jj) {
#pragma unroll
                for (int q = 0; q < 4; ++q) {
                    const int dl = ((c * 4 + jj) << 4) + (q << 2);
                    const int el = (jj << 4) + (q << 2);
                    const float4 a0 = *reinterpret_cast<const float4*>(&xs[tr][dl]);
                    const float4 a1 = *reinterpret_cast<const float4*>(&xs[tr + 16][dl]);
                    const int lb = q << 2;
#pragma unroll
                    for (int j2 = 0; j2 < 2; ++j2) {
                        const float4 b = *reinterpret_cast<const float4*>(&es[cbase + 16 * j2][el]);
                        acc[0][j2][lb + 0] = __builtin_fmaf(a0.x, b.x, acc[0][j2][lb + 0]);
                        acc[0][j2][lb + 1] = __builtin_fmaf(a0.y, b.y, acc[0][j2][lb + 1]);
                        acc[0][j2][lb + 2] = __builtin_fmaf(a0.z, b.z, acc[0][j2][lb + 2]);
                        acc[0][j2][lb + 3] = __builtin_fmaf(a0.w, b.w, acc[0][j2][lb + 3]);
                        acc[1][j2][lb + 0] = __builtin_fmaf(a1.x, b.x, acc[1][j2][lb + 0]);
                        acc[1][j2][lb + 1] = __builtin_fmaf(a1.y, b.y, acc[1][j2][lb + 1]);
                        acc[1][j2][lb + 2] = __builtin_fmaf(a1.z, b.z, acc[1][j2][lb + 2]);
                        acc[1][j2][lb + 3] = __builtin_fmaf(a1.w, b.w, acc[1][j2][lb + 3]);
                    }
                }
            }
        }
#pragma unroll
        for (int j2 = 0; j2 < 2; ++j2) {
            const int kk = k0 + cbase + 16 * j2;
            const float eq = esq[kk];
            {
                const float dist = __fadd_rn(__fsub_rn(xq0, __fmul_rn(2.0f, hsum16_np(acc[0][j2]))), eq);
                const u64 kkey = packkey(dist, (u32)kk);
                best0 = kkey < best0 ? kkey : best0;
            }
            {
                const float dist = __fadd_rn(__fsub_rn(xq1, __fmul_rn(2.0f, hsum16_np(acc[1][j2]))), eq);
                const u64 kkey = packkey(dist, (u32)kk);
                best1 = kkey < best1 ? kkey : best1;
            }
        }
    }
    __syncthreads();
    red[tr * 32 + (g << 4) + tc] = best0;
    red[(tr + 16) * 32 + (g << 4) + tc] = best1;
    __syncthreads();
    if (tid < 32) {
        u64 m = red[tid * 32];
#pragma unroll
        for (int t = 1; t < 32; ++t) {
            u64 v = red[tid * 32 + t];
            m = v < m ? v : m;
        }
        out_idx[n0 + tid] = (int)(m & 0xFFFFFFFFu);
    }
}

// ---------------- downstream (unchanged) ----------------
__global__ void k_scatter(const float* __restrict__ x, const float* __restrict__ embed,
                          const int* __restrict__ idx, float* __restrict__ out,
                          float* __restrict__ loss_acc, float* __restrict__ bins,
                          float* __restrict__ esum, float* __restrict__ ind_out) {
    const int n = blockIdx.x;
    const int d = threadIdx.x;
    const int k = idx[n];
    const size_t xi = ((size_t)n << 8) + d;
    const float xv = x[xi];
    const float qv = embed[((size_t)k << 8) + d];
    const float diff = __fsub_rn(qv, xv);
    out[xi] = __fadd_rn(xv, diff);
    atomicAdd(&esum[((size_t)k << 8) + d], xv);
    __shared__ float sred[256];
    sred[d] = __fmul_rn(diff, diff);
    __syncthreads();
    for (int s = 128; s > 0; s >>= 1) {
        if (d < s) sred[d] += sred[d + s];
        __syncthreads();
    }
    if (d == 0) {
        atomicAdd(loss_acc, sred[0]);
        atomicAdd(&bins[k], 1.0f);
        ind_out[n] = (float)k;
    }
}

__global__ void k_cluster(const float* __restrict__ cs, const float* __restrict__ bins,
                          float* __restrict__ ncs_out, float* __restrict__ n_out) {
    __shared__ float sred[1024];
    const int t = threadIdx.x;
    float s = 0.0f;
    for (int k = t; k < KCODES; k += 1024) {
        const float ncs = __fadd_rn(__fmul_rn(cs[k], 0.1f), __fmul_rn(bins[k], 0.9f));
        ncs_out[k] = ncs;
        s += ncs;
    }
    sred[t] = s;
    __syncthreads();
    for (int w = 512; w > 0; w >>= 1) {
        if (t < w) sred[t] += sred[t + w];
        __syncthreads();
    }
    if (t == 0) n_out[0] = sred[0];
}

__global__ void k_norm(const float* __restrict__ ea, const float* __restrict__ esum,
                       const float* __restrict__ ncs, const float* __restrict__ nptr,
                       float* __restrict__ en_out) {
    const int i = blockIdx.x * 256 + threadIdx.x;
    const int k = i >> 8;
    const float n = nptr[0];
    const float ncsk = ncs[k];
    const float smoothed = (ncsk + 1e-5f) / (n + 4096.0f * 1e-5f) * n;
    const float nea = __fadd_rn(__fmul_rn(ea[i], 0.1f), __fmul_rn(esum[i], 0.9f));
    en_out[i] = nea / smoothed;
}

__global__ void k_loss(const float* __restrict__ acc, float* __restrict__ dst) {
    if (threadIdx.x == 0) dst[0] = acc[0] * (1.0f / 8388608.0f);
}

extern "C" void kernel_launch(void* const* d_in, const int* in_sizes, int n_in, void* d_out,
                              int out_size, void* d_ws, size_t ws_size, hipStream_t stream) {
    (void)in_sizes; (void)n_in; (void)out_size;
    const float* x = (const float*)d_in[0];
    const float* emb = (const float*)d_in[1];
    const float* cs = (const float*)d_in[2];
    const float* ea = (const float*)d_in[3];
    float* ws = (float*)d_ws;
    float* out = (float*)d_out;

    float* w_loss = ws + WS_LOSS;
    u32* w_cnt = (u32*)(ws + WS_CNT);
    float* w_emax = ws + WS_EMAX;
    u32* w_dis = (u32*)(ws + WS_DISTRUST);
    float* w_n = ws + WS_NSC;
    float* w_bins = ws + WS_BINS;
    float* w_esum = ws + WS_ESUM;
    float* w_xsq = ws + WS_XSQ;
    float* w_esq = ws + WS_ESQ;
    int* w_idx = (int*)(ws + WS_IDX);
    u64* w_key = (u64*)(ws + WS_KEY);
    u64* w_tkey = (u64*)(ws + WS_TKEY);
    float* w_tm2 = ws + WS_TM2;
    u32* w_list = (u32*)(ws + WS_LIST);
    ushort* eh_g = (ushort*)(ws + WS_EH);
    ushort* el_g = (ushort*)(ws + WS_EL);

    float* o_out = out;              // [N*D]
    float* o_loss = out + 8388608;   // [1]
    float* o_ind = out + 8388609;    // [N]
    float* o_ncs = out + 8421377;    // [K]
    float* o_en = out + 8425473;     // [K*D]

    // x bf16-split packs live in the o_out region until k_scatter overwrites it
    ushort* xh_g = (ushort*)o_out;
    ushort* xl_g = (ushort*)o_out + 8388608;

    hipMemsetAsync(d_ws, 0, (size_t)WS_ZERO_FLOATS * sizeof(float), stream);

    k_rownorm<<<NROWS / 256, 256, 0, stream>>>(x, w_xsq, NROWS);
    k_rownorm<<<KCODES / 256, 256, 0, stream>>>(emb, w_esq, KCODES);

    if (ws_size >= (size_t)WS_TOTAL * sizeof(float)) {
        k_emax<<<1, 1024, 0, stream>>>(w_esq, w_emax);
        k_pack<<<4096, 256, 0, stream>>>(x, xh_g, xl_g);
        k_pack<<<512, 256, 0, stream>>>(emb, eh_g, el_g);
        k_mfma<<<dim3(256, 8), 256, 0, stream>>>(xh_g, xl_g, eh_g, el_g, w_xsq, w_esq,
                                                 w_tkey, w_tm2);
        k_merge<<<128, 256, 0, stream>>>(w_tkey, w_tm2, w_xsq, w_emax, w_key, w_list, w_cnt);
        k_verify<<<2048, 256, 0, stream>>>(x, emb, w_xsq, w_esq, w_emax, w_key, w_list,
                                           w_cnt, w_dis);
        k_distrust<<<128, 256, 0, stream>>>(w_dis, w_key, w_list, w_cnt);
        k_exact<<<8192, 512, 0, stream>>>(x, emb, w_xsq, w_esq, w_list, w_cnt, w_key);
        k_finalize<<<128, 256, 0, stream>>>(w_key, w_idx);
    } else {
        k_argmin_full<<<NROWS / 32, 512, 0, stream>>>(x, emb, w_xsq, w_esq, w_idx);
    }

    k_scatter<<<NROWS, 256, 0, stream>>>(x, emb, w_idx, o_out, w_loss, w_bins, w_esum, o_ind);
    k_cluster<<<1, 1024, 0, stream>>>(cs, w_bins, o_ncs, w_n);
    k_norm<<<(KCODES * DDIM) / 256, 256, 0, stream>>>(ea, w_esum, o_ncs, w_n, o_en);
    k_loss<<<1, 64, 0, stream>>>(w_loss, o_loss);
}

// Round 9
// 460.946 us; speedup vs baseline: 5.6877x; 1.8164x over previous
//
#include <hip/hip_runtime.h>
#include <hip/hip_bf16.h>
#include <cstdint>
#include <cstddef>

#define NROWS 32768
#define DDIM 256
#define KCODES 4096

typedef __attribute__((ext_vector_type(8))) short s16x8;
typedef __attribute__((ext_vector_type(4))) float f32x4;
typedef unsigned long long u64;
typedef unsigned int u32;

// ---------------- ws layout (float offsets), all 16B-aligned blocks ----------
#define WS_LOSS 0
#define WS_CNT 1
#define WS_EMAX 2
#define WS_DISTRUST 3
#define WS_NSC 4
#define WS_HIST 8                      // u32[4096]
#define WS_OFFS 4104                   // u32[4096]
#define WS_CURSOR 8200                 // u32[4096]
#define WS_LPART 12296                 // f32[4096]
#define WS_RLIST 16392                 // u32[32768]
#define WS_ESUM 49160                  // f32[1048576]
#define WS_XSQ 1097736                 // f32[32768]
#define WS_ESQ 1130504                 // f32[4096]
#define WS_IDX 1134600                 // i32[32768]
#define WS_KEY 1167368                 // u64[32768]
#define WS_TKEY 1232904                // u64[8*32768]
#define WS_TM2 1757192                 // f32[8*32768]
#define WS_LIST 2019336                // u32[32768]
#define WS_EH 2052104                  // ushort[1048576]
#define WS_EL 2576392                  // ushort[1048576]
#define WS_TOTAL 3100680
#define WS_ZERO_FLOATS 12296           // header + hist + offs + cursor

__device__ __forceinline__ float hsum16_np(const float a[16]) {
    float t3[8];
#pragma unroll
    for (int m = 0; m < 8; ++m) t3[m] = __fadd_rn(a[m + 8], a[m]);
    float t6[4];
#pragma unroll
    for (int m = 0; m < 4; ++m) t6[m] = __fadd_rn(t3[m + 4], t3[m]);
    return __fadd_rn(__fadd_rn(t6[0], t6[2]), __fadd_rn(t6[1], t6[3]));
}

__device__ __forceinline__ float np_sum_sq_128(const float* a) {
    float t[16];
#pragma unroll
    for (int l = 0; l < 16; ++l) {
        float m0 = __fmul_rn(a[l], a[l]);
        float m1 = __fmul_rn(a[16 + l], a[16 + l]);
        float m2 = __fmul_rn(a[32 + l], a[32 + l]);
        float m3 = __fmul_rn(a[48 + l], a[48 + l]);
        float m4 = __fmul_rn(a[64 + l], a[64 + l]);
        float m5 = __fmul_rn(a[80 + l], a[80 + l]);
        float m6 = __fmul_rn(a[96 + l], a[96 + l]);
        float m7 = __fmul_rn(a[112 + l], a[112 + l]);
        float s01 = __fadd_rn(m0, m1);
        float s23 = __fadd_rn(m2, m3);
        float s45 = __fadd_rn(m4, m5);
        float s67 = __fadd_rn(m6, m7);
        t[l] = __fadd_rn(__fadd_rn(s01, s23), __fadd_rn(s45, s67));
    }
    return hsum16_np(t);
}

__global__ void k_rownorm(const float* __restrict__ src, float* __restrict__ dst, int rows) {
    int r = blockIdx.x * blockDim.x + threadIdx.x;
    if (r < rows) {
        const float* p = src + ((size_t)r << 8);
        dst[r] = __fadd_rn(np_sum_sq_128(p), np_sum_sq_128(p + 128));
    }
}

__global__ void k_emax(const float* __restrict__ esq, float* __restrict__ emax) {
    __shared__ float s[1024];
    int t = threadIdx.x;
    float m = 0.0f;
    for (int i = t; i < KCODES; i += 1024) m = fmaxf(m, esq[i]);
    s[t] = m;
    __syncthreads();
    for (int w = 512; w > 0; w >>= 1) {
        if (t < w) s[t] = fmaxf(s[t], s[t + w]);
        __syncthreads();
    }
    if (t == 0) emax[0] = s[0];
}

// RNE bf16 from fp32 bits (normal values only here)
__device__ __forceinline__ ushort bf16_rn(float x) {
    u32 u = __float_as_uint(x);
    u32 r = (u + 0x7fffu + ((u >> 16) & 1u)) >> 16;
    return (ushort)r;
}
__device__ __forceinline__ float bf16_f(ushort h) { return __uint_as_float(((u32)h) << 16); }

__global__ void k_pack(const float* __restrict__ src, ushort* __restrict__ hi,
                       ushort* __restrict__ lo) {
    int i = (blockIdx.x * 256 + threadIdx.x) * 8;
    float4 v0 = *reinterpret_cast<const float4*>(src + i);
    float4 v1 = *reinterpret_cast<const float4*>(src + i + 4);
    float f[8] = {v0.x, v0.y, v0.z, v0.w, v1.x, v1.y, v1.z, v1.w};
    ushort h[8], l[8];
#pragma unroll
    for (int j = 0; j < 8; ++j) {
        h[j] = bf16_rn(f[j]);
        l[j] = bf16_rn(__fsub_rn(f[j], bf16_f(h[j])));
    }
    *reinterpret_cast<s16x8*>(hi + i) = *reinterpret_cast<s16x8*>(h);
    *reinterpret_cast<s16x8*>(lo + i) = *reinterpret_cast<s16x8*>(l);
}

__device__ __forceinline__ float keyval_(u64 k) {
    u32 u = (u32)(k >> 32);
    u = (u & 0x80000000u) ? (u ^ 0x80000000u) : ~u;
    return __uint_as_float(u);
}
__device__ __forceinline__ u64 packkey(float d, u32 j) {
    u32 u = __float_as_uint(d);
    u ^= (u32)((int)u >> 31) | 0x80000000u;
    return ((u64)u << 32) | j;
}
#define KEY_INIT 0xFF8000007FFFFFFFull  // packkey(+INF, 0x7fffffff)

__device__ __forceinline__ void dma16(const void* g, void* l) {
    __builtin_amdgcn_global_load_lds(
        (const __attribute__((address_space(1))) void*)g,
        (__attribute__((address_space(3))) void*)l, 16, 0, 0);
}

// Approx distances via bf16-split MFMA (see R7 notes). 256 thr, tile 128n x 512j.
__global__ __attribute__((amdgpu_flat_work_group_size(256, 256), amdgpu_waves_per_eu(3, 3)))
void k_mfma(const ushort* __restrict__ xh_g, const ushort* __restrict__ xl_g,
            const ushort* __restrict__ eh_g, const ushort* __restrict__ el_g,
            const float* __restrict__ xsq, const float* __restrict__ esq,
            u64* __restrict__ tkey, float* __restrict__ tm2) {
    __shared__ __align__(16) ushort xh_s[8192];  // [128][64]
    __shared__ __align__(16) ushort xl_s[8192];
    __shared__ __align__(16) ushort eh_s[4096];  // [64][64]
    __shared__ __align__(16) ushort el_s[4096];

    const int tid = threadIdx.x;
    const int w = tid >> 6, l = tid & 63, lr = l & 15, lg = l >> 4;
    const int n0 = blockIdx.x * 128, jb = blockIdx.y, j0 = jb * 512;
    const int key = (lr & 7) << 4;

    float xq[8];
#pragma unroll
    for (int i = 0; i < 8; ++i)
        xq[i] = xsq[n0 + w * 32 + (i >> 2) * 16 + lg * 4 + (i & 3)];

    u64 K1[8];
    float M2[8];
#pragma unroll
    for (int i = 0; i < 8; ++i) { K1[i] = KEY_INIT; M2[i] = __uint_as_float(0x7F800000u); }

    for (int js = 0; js < 8; ++js) {
        const int jbase = j0 + js * 64;
        f32x4 acc[2][4];
#pragma unroll
        for (int a = 0; a < 2; ++a)
#pragma unroll
            for (int b = 0; b < 4; ++b) acc[a][b] = (f32x4){0.f, 0.f, 0.f, 0.f};

        for (int c = 0; c < 4; ++c) {
            __syncthreads();  // prior phase's reads done
#pragma unroll
            for (int p = 0; p < 4; ++p) {
                int m = tid + p * 256, r = m >> 3, cb = (m & 7) << 4;
                int so = (n0 + r) * 256 + c * 64 + ((cb ^ ((r & 7) << 4)) >> 1);
                dma16(xh_g + so, (char*)xh_s + m * 16);
                dma16(xl_g + so, (char*)xl_s + m * 16);
            }
#pragma unroll
            for (int p = 0; p < 2; ++p) {
                int m = tid + p * 256, r = m >> 3, cb = (m & 7) << 4;
                int so = (jbase + r) * 256 + c * 64 + ((cb ^ ((r & 7) << 4)) >> 1);
                dma16(eh_g + so, (char*)eh_s + m * 16);
                dma16(el_g + so, (char*)el_s + m * 16);
            }
            __syncthreads();  // DMA drained (vmcnt0 before barrier)
#pragma unroll
            for (int ks = 0; ks < 2; ++ks) {
                const int off = (ks * 64 + lg * 16) ^ key;
                s16x8 axh[2], axl[2];
#pragma unroll
                for (int ns = 0; ns < 2; ++ns) {
                    const int row = w * 32 + ns * 16 + lr;
                    axh[ns] = *(const s16x8*)((const char*)(xh_s + row * 64) + off);
                    axl[ns] = *(const s16x8*)((const char*)(xl_s + row * 64) + off);
                }
#pragma unroll
                for (int jp = 0; jp < 2; ++jp) {
                    s16x8 beh[2], bel[2];
#pragma unroll
                    for (int q = 0; q < 2; ++q) {
                        const int row = (jp * 2 + q) * 16 + lr;
                        beh[q] = *(const s16x8*)((const char*)(eh_s + row * 64) + off);
                        bel[q] = *(const s16x8*)((const char*)(el_s + row * 64) + off);
                    }
#pragma unroll
                    for (int q = 0; q < 2; ++q) {
                        const int jsub = jp * 2 + q;
#pragma unroll
                        for (int ns = 0; ns < 2; ++ns) {
                            acc[ns][jsub] = __builtin_amdgcn_mfma_f32_16x16x32_bf16(
                                axh[ns], beh[q], acc[ns][jsub], 0, 0, 0);
                            acc[ns][jsub] = __builtin_amdgcn_mfma_f32_16x16x32_bf16(
                                axh[ns], bel[q], acc[ns][jsub], 0, 0, 0);
                            acc[ns][jsub] = __builtin_amdgcn_mfma_f32_16x16x32_bf16(
                                axl[ns], beh[q], acc[ns][jsub], 0, 0, 0);
                        }
                    }
                }
            }
        }
        // epilogue for this Jstep: d~ with the exact final-op sequence
#pragma unroll
        for (int jsub = 0; jsub < 4; ++jsub) {
            const int j = jbase + jsub * 16 + lr;
            const float eq = esq[j];
#pragma unroll
            for (int ns = 0; ns < 2; ++ns)
#pragma unroll
                for (int r = 0; r < 4; ++r) {
                    const float s = acc[ns][jsub][r];
                    const float d = __fadd_rn(__fsub_rn(xq[ns * 4 + r], __fmul_rn(2.0f, s)), eq);
                    const u64 kk = packkey(d, (u32)j);
                    const int i8 = ns * 4 + r;
                    if (kk < K1[i8]) { M2[i8] = keyval_(K1[i8]); K1[i8] = kk; }
                    else if (d < M2[i8]) M2[i8] = d;
                }
        }
    }
    // cross-lane merge over the 16 j-lanes (masks stay in-group)
#pragma unroll
    for (int i8 = 0; i8 < 8; ++i8) {
        u64 k1 = K1[i8];
        float m2 = M2[i8];
#pragma unroll
        for (int mk = 1; mk < 16; mk <<= 1) {
            u32 klo = __shfl_xor((u32)k1, mk);
            u32 khi = __shfl_xor((u32)(k1 >> 32), mk);
            float om2 = __shfl_xor(m2, mk);
            u64 ok = ((u64)khi << 32) | klo;
            if (ok < k1) { m2 = fminf(om2, keyval_(k1)); k1 = ok; }
            else m2 = fminf(m2, keyval_(ok));
        }
        if (lr == 0) {
            const int n = n0 + w * 32 + (i8 >> 2) * 16 + lg * 4 + (i8 & 3);
            tkey[(size_t)jb * NROWS + n] = k1;
            tm2[(size_t)jb * NROWS + n] = m2;
        }
    }
}

__global__ void k_merge(const u64* __restrict__ tkey, const float* __restrict__ tm2,
                        const float* __restrict__ xsq, const float* __restrict__ emaxp,
                        u64* __restrict__ key64, u32* __restrict__ list, u32* __restrict__ cnt) {
    const int n = blockIdx.x * 256 + threadIdx.x;
    u64 k1 = tkey[n];
    float m2 = tm2[n];
#pragma unroll
    for (int jb = 1; jb < 8; ++jb) {
        u64 ok = tkey[(size_t)jb * NROWS + n];
        float om2 = tm2[(size_t)jb * NROWS + n];
        if (ok < k1) { m2 = fminf(om2, keyval_(k1)); k1 = ok; }
        else m2 = fminf(m2, keyval_(ok));
    }
    const float B = sqrtf(xsq[n] * emaxp[0]);
    const float Ed = 2.4e-4f * B + 1.5e-4f;
    if (m2 - keyval_(k1) <= 2.0f * Ed) {
        key64[n] = ~0ull;
        list[atomicAdd(cnt, 1u)] = (u32)n;
    } else {
        key64[n] = k1;
    }
}

// exact numpy-order dist(n, approx-winner) vs d~(winner): bound-slip / layout guard
__global__ void k_verify(const float* __restrict__ x, const float* __restrict__ e,
                         const float* __restrict__ xsq, const float* __restrict__ esq,
                         const float* __restrict__ emaxp, u64* __restrict__ key64,
                         u32* __restrict__ list, u32* __restrict__ cnt,
                         u32* __restrict__ distrust) {
    const int li = threadIdx.x & 15;
    const int n = blockIdx.x * 16 + (threadIdx.x >> 4);
    const u64 k = key64[n];
    const bool active = (k != ~0ull);
    const int idx = active ? (int)(k & 0xFFFu) : 0;
    const float* xr = x + ((size_t)n << 8);
    const float* er = e + ((size_t)idx << 8);
    float a = 0.0f;
#pragma unroll
    for (int g = 0; g < 4; ++g)
#pragma unroll
        for (int bb = 3; bb >= 0; --bb) {
            const int d = (g * 4 + bb) * 16 + li;
            a = __builtin_fmaf(xr[d], er[d], a);
        }
    const float s1 = __fadd_rn(__shfl_xor(a, 8), a);
    const float s2 = __fadd_rn(__shfl_xor(s1, 4), s1);
    const float u = __fadd_rn(s2, __shfl_xor(s2, 2));
    const float dot = __fadd_rn(u, __shfl_xor(u, 1));
    if (li == 0 && active) {
        const float d = __fadd_rn(__fsub_rn(xsq[n], __fmul_rn(2.0f, dot)), esq[idx]);
        const float dref = keyval_(k);
        const float B = sqrtf(xsq[n] * emaxp[0]);
        const float Ed = 2.4e-4f * B + 1.5e-4f;
        const float diff = fabsf(d - dref);
        if (diff > Ed) {
            key64[n] = ~0ull;
            list[atomicAdd(cnt, 1u)] = (u32)n;
            if (diff > 0.05f) atomicOr(distrust, 1u);
        }
    }
}

__global__ void k_distrust(const u32* __restrict__ distrust, u64* __restrict__ key64,
                           u32* __restrict__ list, u32* __restrict__ cnt) {
    if (*distrust == 0u) return;
    const int n = blockIdx.x * 256 + threadIdx.x;
    key64[n] = ~0ull;
    list[n] = (u32)n;
    if (n == 0) *cnt = (u32)NROWS;
}

// exact numpy-order argmin over a 512-k segment for 32 flagged rows
__global__ __attribute__((amdgpu_flat_work_group_size(512, 512), amdgpu_waves_per_eu(4)))
void k_exact(const float* __restrict__ x, const float* __restrict__ embed,
             const float* __restrict__ xsq, const float* __restrict__ esq,
             const u32* __restrict__ list, const u32* __restrict__ cntp,
             u64* __restrict__ key64) {
    const u32 cnt = *cntp;
    const int grp = blockIdx.x >> 3, seg = blockIdx.x & 7;
    const u32 base = (u32)grp * 32u;
    if (base >= cnt) return;

    __shared__ float xs[32][260];
    __shared__ float es[64][68];
    u64* red = (u64*)&es[0][0];

    const int tid = threadIdx.x;
    const int lane = tid & 63;
    const int w = tid >> 6;
    const int g = w >> 2;
    const int tc = lane & 15;
    const int tr = ((w & 3) << 2) + (lane >> 4);
    const int cbase = (g << 5) + tc;

#pragma unroll
    for (int p = 0; p < 4; ++p) {
        int v = tid + p * 512;
        int r = v >> 6;
        int c4 = (v & 63) << 2;
        u32 row = list[(base + (u32)r < cnt) ? base + r : base];
        const float4 f = *reinterpret_cast<const float4*>(x + ((size_t)row << 8) + c4);
        *reinterpret_cast<float4*>(&xs[r][c4]) = f;
    }

    const u32 row0 = list[(base + (u32)tr < cnt) ? base + tr : base];
    const u32 row1 = list[(base + (u32)tr + 16u < cnt) ? base + tr + 16 : base];
    const float xq0 = xsq[row0];
    const float xq1 = xsq[row1];

    u64 best0 = ~0ull, best1 = ~0ull;

    for (int ktl = 0; ktl < 8; ++ktl) {
        const int k0 = seg * 512 + ktl * 64;
        float acc[2][2][16];
#pragma unroll
        for (int i = 0; i < 2; ++i)
#pragma unroll
            for (int j = 0; j < 2; ++j)
#pragma unroll
                for (int q = 0; q < 16; ++q) acc[i][j][q] = 0.0f;

        for (int c = 0; c < 4; ++c) {
            __syncthreads();
#pragma unroll
            for (int p = 0; p < 2; ++p) {
                int v = tid + p * 512;
                int r = v >> 4;
                int c4 = (v & 15) << 2;
                const float4 f = *reinterpret_cast<const float4*>(
                    embed + ((size_t)(k0 + r) << 8) + (c << 6) + c4);
                *reinterpret_cast<float4*>(&es[r][c4]) = f;
            }
            __syncthreads();
#pragma unroll
            for (int jj = 3; jj >= 0; --jj) {
#pragma unroll
                for (int q = 0; q < 4; ++q) {
                    const int dl = ((c * 4 + jj) << 4) + (q << 2);
                    const int el = (jj << 4) + (q << 2);
                    const float4 a0 = *reinterpret_cast<const float4*>(&xs[tr][dl]);
                    const float4 a1 = *reinterpret_cast<const float4*>(&xs[tr + 16][dl]);
                    const int lb = q << 2;
#pragma unroll
                    for (int j2 = 0; j2 < 2; ++j2) {
                        const float4 b = *reinterpret_cast<const float4*>(&es[cbase + 16 * j2][el]);
                        acc[0][j2][lb + 0] = __builtin_fmaf(a0.x, b.x, acc[0][j2][lb + 0]);
                        acc[0][j2][lb + 1] = __builtin_fmaf(a0.y, b.y, acc[0][j2][lb + 1]);
                        acc[0][j2][lb + 2] = __builtin_fmaf(a0.z, b.z, acc[0][j2][lb + 2]);
                        acc[0][j2][lb + 3] = __builtin_fmaf(a0.w, b.w, acc[0][j2][lb + 3]);
                        acc[1][j2][lb + 0] = __builtin_fmaf(a1.x, b.x, acc[1][j2][lb + 0]);
                        acc[1][j2][lb + 1] = __builtin_fmaf(a1.y, b.y, acc[1][j2][lb + 1]);
                        acc[1][j2][lb + 2] = __builtin_fmaf(a1.z, b.z, acc[1][j2][lb + 2]);
                        acc[1][j2][lb + 3] = __builtin_fmaf(a1.w, b.w, acc[1][j2][lb + 3]);
                    }
                }
            }
        }
#pragma unroll
        for (int j2 = 0; j2 < 2; ++j2) {
            const int kk = k0 + cbase + 16 * j2;
            const float eq = esq[kk];
            {
                const float dist = __fadd_rn(__fsub_rn(xq0, __fmul_rn(2.0f, hsum16_np(acc[0][j2]))), eq);
                const u64 kkey = packkey(dist, (u32)kk);
                best0 = kkey < best0 ? kkey : best0;
            }
            {
                const float dist = __fadd_rn(__fsub_rn(xq1, __fmul_rn(2.0f, hsum16_np(acc[1][j2]))), eq);
                const u64 kkey = packkey(dist, (u32)kk);
                best1 = kkey < best1 ? kkey : best1;
            }
        }
    }

    __syncthreads();
    red[tr * 32 + (g << 4) + tc] = best0;
    red[(tr + 16) * 32 + (g << 4) + tc] = best1;
    __syncthreads();
    if (tid < 32) {
        u64 m = red[tid * 32];
#pragma unroll
        for (int t = 1; t < 32; ++t) {
            u64 v = red[tid * 32 + t];
            m = v < m ? v : m;
        }
        if (base + (u32)tid < cnt) atomicMin(&key64[list[base + tid]], m);
    }
}

__global__ void k_finalize(const u64* __restrict__ key64, int* __restrict__ idx) {
    const int n = blockIdx.x * 256 + threadIdx.x;
    idx[n] = (int)(key64[n] & 0xFFFull);
}

// ---------- fallback full-exact argmin (R6 kernel, known-good) ----------
__global__ __attribute__((amdgpu_flat_work_group_size(512, 512), amdgpu_waves_per_eu(4)))
void k_argmin_full(const float* __restrict__ x, const float* __restrict__ embed,
                   const float* __restrict__ xsq, const float* __restrict__ esq,
                   int* __restrict__ out_idx) {
    __shared__ float xs[32][260];
    __shared__ float es[64][68];
    u64* red = (u64*)&es[0][0];
    const int tid = threadIdx.x;
    const int lane = tid & 63;
    const int w = tid >> 6;
    const int g = w >> 2;
    const int tc = lane & 15;
    const int tr = ((w & 3) << 2) + (lane >> 4);
    const int cbase = (g << 5) + tc;
    const int n0 = blockIdx.x * 32;
#pragma unroll
    for (int p = 0; p < 4; ++p) {
        int v = tid + p * 512;
        int r = v >> 6;
        int c4 = (v & 63) << 2;
        const float4 f = *reinterpret_cast<const float4*>(x + ((size_t)(n0 + r) << 8) + c4);
        *reinterpret_cast<float4*>(&xs[r][c4]) = f;
    }
    const float xq0 = xsq[n0 + tr];
    const float xq1 = xsq[n0 + tr + 16];
    u64 best0 = ~0ull, best1 = ~0ull;
    for (int kt = 0; kt < KCODES / 64; ++kt) {
        const int k0 = kt * 64;
        float acc[2][2][16];
#pragma unroll
        for (int i = 0; i < 2; ++i)
#pragma unroll
            for (int j = 0; j < 2; ++j)
#pragma unroll
                for (int q = 0; q < 16; ++q) acc[i][j][q] = 0.0f;
        for (int c = 0; c < 4; ++c) {
            __syncthreads();
#pragma unroll
            for (int p = 0; p < 2; ++p) {
                int v = tid + p * 512;
                int r = v >> 4;
                int c4 = (v & 15) << 2;
                const float4 f = *reinterpret_cast<const float4*>(
                    embed + ((size_t)(k0 + r) << 8) + (c << 6) + c4);
                *reinterpret_cast<float4*>(&es[r][c4]) = f;
            }
            __syncthreads();
#pragma unroll
            for (int jj = 3; jj >= 0; --jj) {
#pragma unroll
                for (int q = 0; q < 4; ++q) {
                    const int dl = ((c * 4 + jj) << 4) + (q << 2);
                    const int el = (jj << 4) + (q << 2);
                    const float4 a0 = *reinterpret_cast<const float4*>(&xs[tr][dl]);
                    const float4 a1 = *reinterpret_cast<const float4*>(&xs[tr + 16][dl]);
                    const int lb = q << 2;
#pragma unroll
                    for (int j2 = 0; j2 < 2; ++j2) {
                        const float4 b = *reinterpret_cast<const float4*>(&es[cbase + 16 * j2][el]);
                        acc[0][j2][lb + 0] = __builtin_fmaf(a0.x, b.x, acc[0][j2][lb + 0]);
                        acc[0][j2][lb + 1] = __builtin_fmaf(a0.y, b.y, acc[0][j2][lb + 1]);
                        acc[0][j2][lb + 2] = __builtin_fmaf(a0.z, b.z, acc[0][j2][lb + 2]);
                        acc[0][j2][lb + 3] = __builtin_fmaf(a0.w, b.w, acc[0][j2][lb + 3]);
                        acc[1][j2][lb + 0] = __builtin_fmaf(a1.x, b.x, acc[1][j2][lb + 0]);
                        acc[1][j2][lb + 1] = __builtin_fmaf(a1.y, b.y, acc[1][j2][lb + 1]);
                        acc[1][j2][lb + 2] = __builtin_fmaf(a1.z, b.z, acc[1][j2][lb + 2]);
                        acc[1][j2][lb + 3] = __builtin_fmaf(a1.w, b.w, acc[1][j2][lb + 3]);
                    }
                }
            }
        }
#pragma unroll
        for (int j2 = 0; j2 < 2; ++j2) {
            const int kk = k0 + cbase + 16 * j2;
            const float eq = esq[kk];
            {
                const float dist = __fadd_rn(__fsub_rn(xq0, __fmul_rn(2.0f, hsum16_np(acc[0][j2]))), eq);
                const u64 kkey = packkey(dist, (u32)kk);
                best0 = kkey < best0 ? kkey : best0;
            }
            {
                const float dist = __fadd_rn(__fsub_rn(xq1, __fmul_rn(2.0f, hsum16_np(acc[1][j2]))), eq);
                const u64 kkey = packkey(dist, (u32)kk);
                best1 = kkey < best1 ? kkey : best1;
            }
        }
    }
    __syncthreads();
    red[tr * 32 + (g << 4) + tc] = best0;
    red[(tr + 16) * 32 + (g << 4) + tc] = best1;
    __syncthreads();
    if (tid < 32) {
        u64 m = red[tid * 32];
#pragma unroll
        for (int t = 1; t < 32; ++t) {
            u64 v = red[tid * 32 + t];
            m = v < m ? v : m;
        }
        out_idx[n0 + tid] = (int)(m & 0xFFFFFFFFu);
    }
}

// ---------------- atomic-free scatter pipeline (R8) ----------------
// R7's k_scatter was 425us at 1.3% VALUBusy / 2.9% HBM: 32768 blocks all
// atomicAdd one loss address (same-address serialization ~ the whole 425us)
// plus 8.4M esum element atomics. Replaced by histogram + prefix + counting
// sort + per-code gather (zero esum atomics) + partial-sum loss (no global
// atomic on a single address).

__global__ void k_hist(const int* __restrict__ idx, u32* __restrict__ hist,
                       float* __restrict__ ind_out) {
    const int n = blockIdx.x * 256 + threadIdx.x;
    const int k = idx[n];
    atomicAdd(&hist[k], 1u);
    ind_out[n] = (float)k;
}

__global__ void k_scan(const u32* __restrict__ hist, u32* __restrict__ offs) {
    __shared__ u32 ts[1024];
    const int t = threadIdx.x;
    const u32 h0 = hist[t * 4], h1 = hist[t * 4 + 1], h2 = hist[t * 4 + 2], h3 = hist[t * 4 + 3];
    const u32 tot = h0 + h1 + h2 + h3;
    ts[t] = tot;
    __syncthreads();
    for (int o = 1; o < 1024; o <<= 1) {
        const u32 add = (t >= o) ? ts[t - o] : 0u;
        __syncthreads();
        ts[t] += add;
        __syncthreads();
    }
    const u32 excl = ts[t] - tot;
    offs[t * 4] = excl;
    offs[t * 4 + 1] = excl + h0;
    offs[t * 4 + 2] = excl + h0 + h1;
    offs[t * 4 + 3] = excl + h0 + h1 + h2;
}

__global__ void k_place(const int* __restrict__ idx, u32* __restrict__ cursor,
                        const u32* __restrict__ offs, u32* __restrict__ rlist) {
    const int n = blockIdx.x * 256 + threadIdx.x;
    const int k = idx[n];
    const u32 p = atomicAdd(&cursor[k], 1u);
    rlist[offs[k] + p] = (u32)n;
}

__global__ void k_esum(const float* __restrict__ x, const u32* __restrict__ rlist,
                       const u32* __restrict__ offs, const u32* __restrict__ hist,
                       float* __restrict__ esum) {
    const int k = blockIdx.x;
    const int d = threadIdx.x;
    const u32 o = offs[k], c = hist[k];
    float s = 0.0f;
    for (u32 i = 0; i < c; ++i) s += x[((size_t)rlist[o + i] << 8) + d];
    esum[((size_t)k << 8) + d] = s;
}

__global__ void k_outloss(const float* __restrict__ x, const float* __restrict__ e,
                          const int* __restrict__ idx, float* __restrict__ out,
                          float* __restrict__ lpart) {
    const int d = threadIdx.x;
    float ls = 0.0f;
#pragma unroll
    for (int r = 0; r < 8; ++r) {
        const int n = blockIdx.x * 8 + r;
        const int k = idx[n];
        const size_t xi = ((size_t)n << 8) + d;
        const float xv = x[xi];
        const float qv = e[((size_t)k << 8) + d];
        const float diff = __fsub_rn(qv, xv);
        out[xi] = __fadd_rn(xv, diff);
        ls = __builtin_fmaf(diff, diff, ls);
    }
    __shared__ float sred[256];
    sred[d] = ls;
    __syncthreads();
    for (int s = 128; s > 0; s >>= 1) {
        if (d < s) sred[d] += sred[d + s];
        __syncthreads();
    }
    if (d == 0) lpart[blockIdx.x] = sred[0];
}

__global__ void k_cluster(const float* __restrict__ cs, const u32* __restrict__ hist,
                          float* __restrict__ ncs_out, float* __restrict__ n_out) {
    __shared__ float sred[1024];
    const int t = threadIdx.x;
    float s = 0.0f;
    for (int k = t; k < KCODES; k += 1024) {
        const float ncs = __fadd_rn(__fmul_rn(cs[k], 0.1f), __fmul_rn((float)hist[k], 0.9f));
        ncs_out[k] = ncs;
        s += ncs;
    }
    sred[t] = s;
    __syncthreads();
    for (int w = 512; w > 0; w >>= 1) {
        if (t < w) sred[t] += sred[t + w];
        __syncthreads();
    }
    if (t == 0) n_out[0] = sred[0];
}

__global__ void k_norm(const float* __restrict__ ea, const float* __restrict__ esum,
                       const float* __restrict__ ncs, const float* __restrict__ nptr,
                       float* __restrict__ en_out) {
    const int i = blockIdx.x * 256 + threadIdx.x;
    const int k = i >> 8;
    const float n = nptr[0];
    const float ncsk = ncs[k];
    const float smoothed = (ncsk + 1e-5f) / (n + 4096.0f * 1e-5f) * n;
    const float nea = __fadd_rn(__fmul_rn(ea[i], 0.1f), __fmul_rn(esum[i], 0.9f));
    en_out[i] = nea / smoothed;
}

__global__ void k_loss(const float* __restrict__ lpart, float* __restrict__ dst) {
    __shared__ float s[256];
    const int t = threadIdx.x;
    float a = 0.0f;
    for (int i = t; i < 4096; i += 256) a += lpart[i];
    s[t] = a;
    __syncthreads();
    for (int w = 128; w > 0; w >>= 1) {
        if (t < w) s[t] += s[t + w];
        __syncthreads();
    }
    if (t == 0) dst[0] = s[0] * (1.0f / 8388608.0f);
}

extern "C" void kernel_launch(void* const* d_in, const int* in_sizes, int n_in, void* d_out,
                              int out_size, void* d_ws, size_t ws_size, hipStream_t stream) {
    (void)in_sizes; (void)n_in; (void)out_size;
    const float* x = (const float*)d_in[0];
    const float* emb = (const float*)d_in[1];
    const float* cs = (const float*)d_in[2];
    const float* ea = (const float*)d_in[3];
    float* ws = (float*)d_ws;
    float* out = (float*)d_out;

    u32* w_cnt = (u32*)(ws + WS_CNT);
    float* w_emax = ws + WS_EMAX;
    u32* w_dis = (u32*)(ws + WS_DISTRUST);
    float* w_n = ws + WS_NSC;
    u32* w_hist = (u32*)(ws + WS_HIST);
    u32* w_offs = (u32*)(ws + WS_OFFS);
    u32* w_cursor = (u32*)(ws + WS_CURSOR);
    float* w_lpart = ws + WS_LPART;
    u32* w_rlist = (u32*)(ws + WS_RLIST);
    float* w_esum = ws + WS_ESUM;
    float* w_xsq = ws + WS_XSQ;
    float* w_esq = ws + WS_ESQ;
    int* w_idx = (int*)(ws + WS_IDX);
    u64* w_key = (u64*)(ws + WS_KEY);
    u64* w_tkey = (u64*)(ws + WS_TKEY);
    float* w_tm2 = ws + WS_TM2;
    u32* w_list = (u32*)(ws + WS_LIST);
    ushort* eh_g = (ushort*)(ws + WS_EH);
    ushort* el_g = (ushort*)(ws + WS_EL);

    float* o_out = out;              // [N*D]
    float* o_loss = out + 8388608;   // [1]
    float* o_ind = out + 8388609;    // [N]
    float* o_ncs = out + 8421377;    // [K]
    float* o_en = out + 8425473;     // [K*D]

    // x bf16-split packs live in the o_out region until k_outloss overwrites it
    ushort* xh_g = (ushort*)o_out;
    ushort* xl_g = (ushort*)o_out + 8388608;

    // zero header + hist + offs + cursor only (esum now fully overwritten by gather)
    hipMemsetAsync(d_ws, 0, (size_t)WS_ZERO_FLOATS * sizeof(float), stream);

    k_rownorm<<<NROWS / 256, 256, 0, stream>>>(x, w_xsq, NROWS);
    k_rownorm<<<KCODES / 256, 256, 0, stream>>>(emb, w_esq, KCODES);

    if (ws_size >= (size_t)WS_TOTAL * sizeof(float)) {
        k_emax<<<1, 1024, 0, stream>>>(w_esq, w_emax);
        k_pack<<<4096, 256, 0, stream>>>(x, xh_g, xl_g);
        k_pack<<<512, 256, 0, stream>>>(emb, eh_g, el_g);
        k_mfma<<<dim3(256, 8), 256, 0, stream>>>(xh_g, xl_g, eh_g, el_g, w_xsq, w_esq,
                                                 w_tkey, w_tm2);
        k_merge<<<128, 256, 0, stream>>>(w_tkey, w_tm2, w_xsq, w_emax, w_key, w_list, w_cnt);
        k_verify<<<2048, 256, 0, stream>>>(x, emb, w_xsq, w_esq, w_emax, w_key, w_list,
                                           w_cnt, w_dis);
        k_distrust<<<128, 256, 0, stream>>>(w_dis, w_key, w_list, w_cnt);
        k_exact<<<8192, 512, 0, stream>>>(x, emb, w_xsq, w_esq, w_list, w_cnt, w_key);
        k_finalize<<<128, 256, 0, stream>>>(w_key, w_idx);
    } else {
        k_argmin_full<<<NROWS / 32, 512, 0, stream>>>(x, emb, w_xsq, w_esq, w_idx);
    }

    // atomic-free scatter pipeline
    k_hist<<<128, 256, 0, stream>>>(w_idx, w_hist, o_ind);
    k_scan<<<1, 1024, 0, stream>>>(w_hist, w_offs);
    k_place<<<128, 256, 0, stream>>>(w_idx, w_cursor, w_offs, w_rlist);
    k_esum<<<KCODES, 256, 0, stream>>>(x, w_rlist, w_offs, w_hist, w_esum);
    k_outloss<<<NROWS / 8, 256, 0, stream>>>(x, emb, w_idx, o_out, w_lpart);
    k_cluster<<<1, 1024, 0, stream>>>(cs, w_hist, o_ncs, w_n);
    k_norm<<<(KCODES * DDIM) / 256, 256, 0, stream>>>(ea, w_esum, o_ncs, w_n, o_en);
    k_loss<<<1, 256, 0, stream>>>(w_lpart, o_loss);
}

// Round 10
// 448.868 us; speedup vs baseline: 5.8408x; 1.0269x over previous
//
#include <hip/hip_runtime.h>
#include <hip/hip_bf16.h>
#include <cstdint>
#include <cstddef>

#define NROWS 32768
#define DDIM 256
#define KCODES 4096

typedef __attribute__((ext_vector_type(8))) short s16x8;
typedef __attribute__((ext_vector_type(4))) float f32x4;
typedef unsigned long long u64;
typedef unsigned int u32;

// ---------------- ws layout (float offsets), all 16B-aligned blocks ----------
#define WS_LOSS 0
#define WS_CNT 1
#define WS_EMAX 2
#define WS_DISTRUST 3
#define WS_NSC 4
#define WS_HIST 8                      // u32[4096]
#define WS_OFFS 4104                   // u32[4096]
#define WS_CURSOR 8200                 // u32[4096]
#define WS_LPART 12296                 // f32[4096]
#define WS_RLIST 16392                 // u32[32768]
#define WS_ESUM 49160                  // f32[1048576]
#define WS_XSQ 1097736                 // f32[32768]
#define WS_ESQ 1130504                 // f32[4096]
#define WS_IDX 1134600                 // i32[32768]
#define WS_KEY 1167368                 // u64[32768]
#define WS_TKEY 1232904                // u64[8*32768]
#define WS_TM2 1757192                 // f32[8*32768]
#define WS_LIST 2019336                // u32[32768]
#define WS_EH 2052104                  // ushort[1048576]
#define WS_EL 2576392                  // ushort[1048576]
#define WS_TOTAL 3100680
#define WS_ZERO_FLOATS 12296           // header + hist + offs + cursor

__device__ __forceinline__ float hsum16_np(const float a[16]) {
    float t3[8];
#pragma unroll
    for (int m = 0; m < 8; ++m) t3[m] = __fadd_rn(a[m + 8], a[m]);
    float t6[4];
#pragma unroll
    for (int m = 0; m < 4; ++m) t6[m] = __fadd_rn(t3[m + 4], t3[m]);
    return __fadd_rn(__fadd_rn(t6[0], t6[2]), __fadd_rn(t6[1], t6[3]));
}

__device__ __forceinline__ float np_sum_sq_128(const float* a) {
    float t[16];
#pragma unroll
    for (int l = 0; l < 16; ++l) {
        float m0 = __fmul_rn(a[l], a[l]);
        float m1 = __fmul_rn(a[16 + l], a[16 + l]);
        float m2 = __fmul_rn(a[32 + l], a[32 + l]);
        float m3 = __fmul_rn(a[48 + l], a[48 + l]);
        float m4 = __fmul_rn(a[64 + l], a[64 + l]);
        float m5 = __fmul_rn(a[80 + l], a[80 + l]);
        float m6 = __fmul_rn(a[96 + l], a[96 + l]);
        float m7 = __fmul_rn(a[112 + l], a[112 + l]);
        float s01 = __fadd_rn(m0, m1);
        float s23 = __fadd_rn(m2, m3);
        float s45 = __fadd_rn(m4, m5);
        float s67 = __fadd_rn(m6, m7);
        t[l] = __fadd_rn(__fadd_rn(s01, s23), __fadd_rn(s45, s67));
    }
    return hsum16_np(t);
}

__global__ void k_rownorm(const float* __restrict__ src, float* __restrict__ dst, int rows) {
    int r = blockIdx.x * blockDim.x + threadIdx.x;
    if (r < rows) {
        const float* p = src + ((size_t)r << 8);
        dst[r] = __fadd_rn(np_sum_sq_128(p), np_sum_sq_128(p + 128));
    }
}

__global__ void k_emax(const float* __restrict__ esq, float* __restrict__ emax) {
    __shared__ float s[1024];
    int t = threadIdx.x;
    float m = 0.0f;
    for (int i = t; i < KCODES; i += 1024) m = fmaxf(m, esq[i]);
    s[t] = m;
    __syncthreads();
    for (int w = 512; w > 0; w >>= 1) {
        if (t < w) s[t] = fmaxf(s[t], s[t + w]);
        __syncthreads();
    }
    if (t == 0) emax[0] = s[0];
}

// RNE bf16 from fp32 bits (normal values only here)
__device__ __forceinline__ ushort bf16_rn(float x) {
    u32 u = __float_as_uint(x);
    u32 r = (u + 0x7fffu + ((u >> 16) & 1u)) >> 16;
    return (ushort)r;
}
__device__ __forceinline__ float bf16_f(ushort h) { return __uint_as_float(((u32)h) << 16); }

__global__ void k_pack(const float* __restrict__ src, ushort* __restrict__ hi,
                       ushort* __restrict__ lo) {
    int i = (blockIdx.x * 256 + threadIdx.x) * 8;
    float4 v0 = *reinterpret_cast<const float4*>(src + i);
    float4 v1 = *reinterpret_cast<const float4*>(src + i + 4);
    float f[8] = {v0.x, v0.y, v0.z, v0.w, v1.x, v1.y, v1.z, v1.w};
    ushort h[8], l[8];
#pragma unroll
    for (int j = 0; j < 8; ++j) {
        h[j] = bf16_rn(f[j]);
        l[j] = bf16_rn(__fsub_rn(f[j], bf16_f(h[j])));
    }
    *reinterpret_cast<s16x8*>(hi + i) = *reinterpret_cast<s16x8*>(h);
    *reinterpret_cast<s16x8*>(lo + i) = *reinterpret_cast<s16x8*>(l);
}

__device__ __forceinline__ float keyval_(u64 k) {
    u32 u = (u32)(k >> 32);
    u = (u & 0x80000000u) ? (u ^ 0x80000000u) : ~u;
    return __uint_as_float(u);
}
__device__ __forceinline__ u64 packkey(float d, u32 j) {
    u32 u = __float_as_uint(d);
    u ^= (u32)((int)u >> 31) | 0x80000000u;
    return ((u64)u << 32) | j;
}
#define KEY_INIT 0xFF8000007FFFFFFFull  // packkey(+INF, 0x7fffffff)

__device__ __forceinline__ void dma16(const void* g, void* l) {
    __builtin_amdgcn_global_load_lds(
        (const __attribute__((address_space(1))) void*)g,
        (__attribute__((address_space(3))) void*)l, 16, 0, 0);
}

// Approx distances via bf16-split MFMA.
// R9 geometry: 512 thr (8 waves), tile 256n x 512j, 1024 blocks (was 2048).
// LDS 80KB = xh/xl[256][64] (32+32) + eh/el[64][64] (8+8) -> exactly 2
// blocks/CU (16 waves/CU, 50%); waves_per_eu(4,4) pins the 128-VGPR bucket
// (kernel uses ~68 - no allocator trap). vs R8: per-CU phase count halves
// (128 vmcnt-drains + barrier pairs), e-DMA bytes halve, 10 dma16/thread/
// phase (was 12). Per-(n,j) MFMA sequence bit-identical to R8.
__global__ __attribute__((amdgpu_flat_work_group_size(512, 512), amdgpu_waves_per_eu(4, 4)))
void k_mfma(const ushort* __restrict__ xh_g, const ushort* __restrict__ xl_g,
            const ushort* __restrict__ eh_g, const ushort* __restrict__ el_g,
            const float* __restrict__ xsq, const float* __restrict__ esq,
            u64* __restrict__ tkey, float* __restrict__ tm2) {
    __shared__ __align__(16) ushort xh_s[16384];  // [256][64]
    __shared__ __align__(16) ushort xl_s[16384];
    __shared__ __align__(16) ushort eh_s[4096];   // [64][64]
    __shared__ __align__(16) ushort el_s[4096];

    const int tid = threadIdx.x;
    const int w = tid >> 6, l = tid & 63, lr = l & 15, lg = l >> 4;
    const int n0 = blockIdx.x * 256, jb = blockIdx.y, j0 = jb * 512;
    const int key = (lr & 7) << 4;

    float xq[8];
#pragma unroll
    for (int i = 0; i < 8; ++i)
        xq[i] = xsq[n0 + w * 32 + (i >> 2) * 16 + lg * 4 + (i & 3)];

    u64 K1[8];
    float M2[8];
#pragma unroll
    for (int i = 0; i < 8; ++i) { K1[i] = KEY_INIT; M2[i] = __uint_as_float(0x7F800000u); }

    for (int js = 0; js < 8; ++js) {
        const int jbase = j0 + js * 64;
        f32x4 acc[2][4];
#pragma unroll
        for (int a = 0; a < 2; ++a)
#pragma unroll
            for (int b = 0; b < 4; ++b) acc[a][b] = (f32x4){0.f, 0.f, 0.f, 0.f};

        for (int c = 0; c < 4; ++c) {
            __syncthreads();  // prior phase's reads done
#pragma unroll
            for (int p = 0; p < 4; ++p) {
                int m = tid + p * 512, r = m >> 3, cb = (m & 7) << 4;
                int so = (n0 + r) * 256 + c * 64 + ((cb ^ ((r & 7) << 4)) >> 1);
                dma16(xh_g + so, (char*)xh_s + m * 16);
                dma16(xl_g + so, (char*)xl_s + m * 16);
            }
            {
                int m = tid, r = m >> 3, cb = (m & 7) << 4;
                int so = (jbase + r) * 256 + c * 64 + ((cb ^ ((r & 7) << 4)) >> 1);
                dma16(eh_g + so, (char*)eh_s + m * 16);
                dma16(el_g + so, (char*)el_s + m * 16);
            }
            __syncthreads();  // DMA drained (vmcnt0 before barrier)
#pragma unroll
            for (int ks = 0; ks < 2; ++ks) {
                const int off = (ks * 64 + lg * 16) ^ key;
                s16x8 axh[2], axl[2];
#pragma unroll
                for (int ns = 0; ns < 2; ++ns) {
                    const int row = w * 32 + ns * 16 + lr;
                    axh[ns] = *(const s16x8*)((const char*)(xh_s + row * 64) + off);
                    axl[ns] = *(const s16x8*)((const char*)(xl_s + row * 64) + off);
                }
#pragma unroll
                for (int jp = 0; jp < 2; ++jp) {
                    s16x8 beh[2], bel[2];
#pragma unroll
                    for (int q = 0; q < 2; ++q) {
                        const int row = (jp * 2 + q) * 16 + lr;
                        beh[q] = *(const s16x8*)((const char*)(eh_s + row * 64) + off);
                        bel[q] = *(const s16x8*)((const char*)(el_s + row * 64) + off);
                    }
#pragma unroll
                    for (int q = 0; q < 2; ++q) {
                        const int jsub = jp * 2 + q;
#pragma unroll
                        for (int ns = 0; ns < 2; ++ns) {
                            acc[ns][jsub] = __builtin_amdgcn_mfma_f32_16x16x32_bf16(
                                axh[ns], beh[q], acc[ns][jsub], 0, 0, 0);
                            acc[ns][jsub] = __builtin_amdgcn_mfma_f32_16x16x32_bf16(
                                axh[ns], bel[q], acc[ns][jsub], 0, 0, 0);
                            acc[ns][jsub] = __builtin_amdgcn_mfma_f32_16x16x32_bf16(
                                axl[ns], beh[q], acc[ns][jsub], 0, 0, 0);
                        }
                    }
                }
            }
        }
        // epilogue for this Jstep: d~ with the exact final-op sequence
#pragma unroll
        for (int jsub = 0; jsub < 4; ++jsub) {
            const int j = jbase + jsub * 16 + lr;
            const float eq = esq[j];
#pragma unroll
            for (int ns = 0; ns < 2; ++ns)
#pragma unroll
                for (int r = 0; r < 4; ++r) {
                    const float s = acc[ns][jsub][r];
                    const float d = __fadd_rn(__fsub_rn(xq[ns * 4 + r], __fmul_rn(2.0f, s)), eq);
                    const u64 kk = packkey(d, (u32)j);
                    const int i8 = ns * 4 + r;
                    if (kk < K1[i8]) { M2[i8] = keyval_(K1[i8]); K1[i8] = kk; }
                    else if (d < M2[i8]) M2[i8] = d;
                }
        }
    }
    // cross-lane merge over the 16 j-lanes (masks stay in-group)
#pragma unroll
    for (int i8 = 0; i8 < 8; ++i8) {
        u64 k1 = K1[i8];
        float m2 = M2[i8];
#pragma unroll
        for (int mk = 1; mk < 16; mk <<= 1) {
            u32 klo = __shfl_xor((u32)k1, mk);
            u32 khi = __shfl_xor((u32)(k1 >> 32), mk);
            float om2 = __shfl_xor(m2, mk);
            u64 ok = ((u64)khi << 32) | klo;
            if (ok < k1) { m2 = fminf(om2, keyval_(k1)); k1 = ok; }
            else m2 = fminf(m2, keyval_(ok));
        }
        if (lr == 0) {
            const int n = n0 + w * 32 + (i8 >> 2) * 16 + lg * 4 + (i8 & 3);
            tkey[(size_t)jb * NROWS + n] = k1;
            tm2[(size_t)jb * NROWS + n] = m2;
        }
    }
}

__global__ void k_merge(const u64* __restrict__ tkey, const float* __restrict__ tm2,
                        const float* __restrict__ xsq, const float* __restrict__ emaxp,
                        u64* __restrict__ key64, u32* __restrict__ list, u32* __restrict__ cnt) {
    const int n = blockIdx.x * 256 + threadIdx.x;
    u64 k1 = tkey[n];
    float m2 = tm2[n];
#pragma unroll
    for (int jb = 1; jb < 8; ++jb) {
        u64 ok = tkey[(size_t)jb * NROWS + n];
        float om2 = tm2[(size_t)jb * NROWS + n];
        if (ok < k1) { m2 = fminf(om2, keyval_(k1)); k1 = ok; }
        else m2 = fminf(m2, keyval_(ok));
    }
    const float B = sqrtf(xsq[n] * emaxp[0]);
    const float Ed = 2.4e-4f * B + 1.5e-4f;
    if (m2 - keyval_(k1) <= 2.0f * Ed) {
        key64[n] = ~0ull;
        list[atomicAdd(cnt, 1u)] = (u32)n;
    } else {
        key64[n] = k1;
    }
}

// exact numpy-order dist(n, approx-winner) vs d~(winner): bound-slip / layout guard
__global__ void k_verify(const float* __restrict__ x, const float* __restrict__ e,
                         const float* __restrict__ xsq, const float* __restrict__ esq,
                         const float* __restrict__ emaxp, u64* __restrict__ key64,
                         u32* __restrict__ list, u32* __restrict__ cnt,
                         u32* __restrict__ distrust) {
    const int li = threadIdx.x & 15;
    const int n = blockIdx.x * 16 + (threadIdx.x >> 4);
    const u64 k = key64[n];
    const bool active = (k != ~0ull);
    const int idx = active ? (int)(k & 0xFFFu) : 0;
    const float* xr = x + ((size_t)n << 8);
    const float* er = e + ((size_t)idx << 8);
    float a = 0.0f;
#pragma unroll
    for (int g = 0; g < 4; ++g)
#pragma unroll
        for (int bb = 3; bb >= 0; --bb) {
            const int d = (g * 4 + bb) * 16 + li;
            a = __builtin_fmaf(xr[d], er[d], a);
        }
    const float s1 = __fadd_rn(__shfl_xor(a, 8), a);
    const float s2 = __fadd_rn(__shfl_xor(s1, 4), s1);
    const float u = __fadd_rn(s2, __shfl_xor(s2, 2));
    const float dot = __fadd_rn(u, __shfl_xor(u, 1));
    if (li == 0 && active) {
        const float d = __fadd_rn(__fsub_rn(xsq[n], __fmul_rn(2.0f, dot)), esq[idx]);
        const float dref = keyval_(k);
        const float B = sqrtf(xsq[n] * emaxp[0]);
        const float Ed = 2.4e-4f * B + 1.5e-4f;
        const float diff = fabsf(d - dref);
        if (diff > Ed) {
            key64[n] = ~0ull;
            list[atomicAdd(cnt, 1u)] = (u32)n;
            if (diff > 0.05f) atomicOr(distrust, 1u);
        }
    }
}

__global__ void k_distrust(const u32* __restrict__ distrust, u64* __restrict__ key64,
                           u32* __restrict__ list, u32* __restrict__ cnt) {
    if (*distrust == 0u) return;
    const int n = blockIdx.x * 256 + threadIdx.x;
    key64[n] = ~0ull;
    list[n] = (u32)n;
    if (n == 0) *cnt = (u32)NROWS;
}

// exact numpy-order argmin over a 512-k segment for 32 flagged rows
__global__ __attribute__((amdgpu_flat_work_group_size(512, 512), amdgpu_waves_per_eu(4)))
void k_exact(const float* __restrict__ x, const float* __restrict__ embed,
             const float* __restrict__ xsq, const float* __restrict__ esq,
             const u32* __restrict__ list, const u32* __restrict__ cntp,
             u64* __restrict__ key64) {
    const u32 cnt = *cntp;
    const int grp = blockIdx.x >> 3, seg = blockIdx.x & 7;
    const u32 base = (u32)grp * 32u;
    if (base >= cnt) return;

    __shared__ float xs[32][260];
    __shared__ float es[64][68];
    u64* red = (u64*)&es[0][0];

    const int tid = threadIdx.x;
    const int lane = tid & 63;
    const int w = tid >> 6;
    const int g = w >> 2;
    const int tc = lane & 15;
    const int tr = ((w & 3) << 2) + (lane >> 4);
    const int cbase = (g << 5) + tc;

#pragma unroll
    for (int p = 0; p < 4; ++p) {
        int v = tid + p * 512;
        int r = v >> 6;
        int c4 = (v & 63) << 2;
        u32 row = list[(base + (u32)r < cnt) ? base + r : base];
        const float4 f = *reinterpret_cast<const float4*>(x + ((size_t)row << 8) + c4);
        *reinterpret_cast<float4*>(&xs[r][c4]) = f;
    }

    const u32 row0 = list[(base + (u32)tr < cnt) ? base + tr : base];
    const u32 row1 = list[(base + (u32)tr + 16u < cnt) ? base + tr + 16 : base];
    const float xq0 = xsq[row0];
    const float xq1 = xsq[row1];

    u64 best0 = ~0ull, best1 = ~0ull;

    for (int ktl = 0; ktl < 8; ++ktl) {
        const int k0 = seg * 512 + ktl * 64;
        float acc[2][2][16];
#pragma unroll
        for (int i = 0; i < 2; ++i)
#pragma unroll
            for (int j = 0; j < 2; ++j)
#pragma unroll
                for (int q = 0; q < 16; ++q) acc[i][j][q] = 0.0f;

        for (int c = 0; c < 4; ++c) {
            __syncthreads();
#pragma unroll
            for (int p = 0; p < 2; ++p) {
                int v = tid + p * 512;
                int r = v >> 4;
                int c4 = (v & 15) << 2;
                const float4 f = *reinterpret_cast<const float4*>(
                    embed + ((size_t)(k0 + r) << 8) + (c << 6) + c4);
                *reinterpret_cast<float4*>(&es[r][c4]) = f;
            }
            __syncthreads();
#pragma unroll
            for (int jj = 3; jj >= 0; --jj) {
#pragma unroll
                for (int q = 0; q < 4; ++q) {
                    const int dl = ((c * 4 + jj) << 4) + (q << 2);
                    const int el = (jj << 4) + (q << 2);
                    const float4 a0 = *reinterpret_cast<const float4*>(&xs[tr][dl]);
                    const float4 a1 = *reinterpret_cast<const float4*>(&xs[tr + 16][dl]);
                    const int lb = q << 2;
#pragma unroll
                    for (int j2 = 0; j2 < 2; ++j2) {
                        const float4 b = *reinterpret_cast<const float4*>(&es[cbase + 16 * j2][el]);
                        acc[0][j2][lb + 0] = __builtin_fmaf(a0.x, b.x, acc[0][j2][lb + 0]);
                        acc[0][j2][lb + 1] = __builtin_fmaf(a0.y, b.y, acc[0][j2][lb + 1]);
                        acc[0][j2][lb + 2] = __builtin_fmaf(a0.z, b.z, acc[0][j2][lb + 2]);
                        acc[0][j2][lb + 3] = __builtin_fmaf(a0.w, b.w, acc[0][j2][lb + 3]);
                        acc[1][j2][lb + 0] = __builtin_fmaf(a1.x, b.x, acc[1][j2][lb + 0]);
                        acc[1][j2][lb + 1] = __builtin_fmaf(a1.y, b.y, acc[1][j2][lb + 1]);
                        acc[1][j2][lb + 2] = __builtin_fmaf(a1.z, b.z, acc[1][j2][lb + 2]);
                        acc[1][j2][lb + 3] = __builtin_fmaf(a1.w, b.w, acc[1][j2][lb + 3]);
                    }
                }
            }
        }
#pragma unroll
        for (int j2 = 0; j2 < 2; ++j2) {
            const int kk = k0 + cbase + 16 * j2;
            const float eq = esq[kk];
            {
                const float dist = __fadd_rn(__fsub_rn(xq0, __fmul_rn(2.0f, hsum16_np(acc[0][j2]))), eq);
                const u64 kkey = packkey(dist, (u32)kk);
                best0 = kkey < best0 ? kkey : best0;
            }
            {
                const float dist = __fadd_rn(__fsub_rn(xq1, __fmul_rn(2.0f, hsum16_np(acc[1][j2]))), eq);
                const u64 kkey = packkey(dist, (u32)kk);
                best1 = kkey < best1 ? kkey : best1;
            }
        }
    }

    __syncthreads();
    red[tr * 32 + (g << 4) + tc] = best0;
    red[(tr + 16) * 32 + (g << 4) + tc] = best1;
    __syncthreads();
    if (tid < 32) {
        u64 m = red[tid * 32];
#pragma unroll
        for (int t = 1; t < 32; ++t) {
            u64 v = red[tid * 32 + t];
            m = v < m ? v : m;
        }
        if (base + (u32)tid < cnt) atomicMin(&key64[list[base + tid]], m);
    }
}

// finalize idx + histogram + ind_out in one pass (fused R8's k_finalize+k_hist)
__global__ void k_finhist(const u64* __restrict__ key64, int* __restrict__ idx,
                          u32* __restrict__ hist, float* __restrict__ ind_out) {
    const int n = blockIdx.x * 256 + threadIdx.x;
    const int k = (int)(key64[n] & 0xFFFull);
    idx[n] = k;
    atomicAdd(&hist[k], 1u);
    ind_out[n] = (float)k;
}

// ---------- fallback full-exact argmin (R6 kernel, known-good) ----------
__global__ __attribute__((amdgpu_flat_work_group_size(512, 512), amdgpu_waves_per_eu(4)))
void k_argmin_full(const float* __restrict__ x, const float* __restrict__ embed,
                   const float* __restrict__ xsq, const float* __restrict__ esq,
                   int* __restrict__ out_idx) {
    __shared__ float xs[32][260];
    __shared__ float es[64][68];
    u64* red = (u64*)&es[0][0];
    const int tid = threadIdx.x;
    const int lane = tid & 63;
    const int w = tid >> 6;
    const int g = w >> 2;
    const int tc = lane & 15;
    const int tr = ((w & 3) << 2) + (lane >> 4);
    const int cbase = (g << 5) + tc;
    const int n0 = blockIdx.x * 32;
#pragma unroll
    for (int p = 0; p < 4; ++p) {
        int v = tid + p * 512;
        int r = v >> 6;
        int c4 = (v & 63) << 2;
        const float4 f = *reinterpret_cast<const float4*>(x + ((size_t)(n0 + r) << 8) + c4);
        *reinterpret_cast<float4*>(&xs[r][c4]) = f;
    }
    const float xq0 = xsq[n0 + tr];
    const float xq1 = xsq[n0 + tr + 16];
    u64 best0 = ~0ull, best1 = ~0ull;
    for (int kt = 0; kt < KCODES / 64; ++kt) {
        const int k0 = kt * 64;
        float acc[2][2][16];
#pragma unroll
        for (int i = 0; i < 2; ++i)
#pragma unroll
            for (int j = 0; j < 2; ++j)
#pragma unroll
                for (int q = 0; q < 16; ++q) acc[i][j][q] = 0.0f;
        for (int c = 0; c < 4; ++c) {
            __syncthreads();
#pragma unroll
            for (int p = 0; p < 2; ++p) {
                int v = tid + p * 512;
                int r = v >> 4;
                int c4 = (v & 15) << 2;
                const float4 f = *reinterpret_cast<const float4*>(
                    embed + ((size_t)(k0 + r) << 8) + (c << 6) + c4);
                *reinterpret_cast<float4*>(&es[r][c4]) = f;
            }
            __syncthreads();
#pragma unroll
            for (int jj = 3; jj >= 0; --jj) {
#pragma unroll
                for (int q = 0; q < 4; ++q) {
                    const int dl = ((c * 4 + jj) << 4) + (q << 2);
                    const int el = (jj << 4) + (q << 2);
                    const float4 a0 = *reinterpret_cast<const float4*>(&xs[tr][dl]);
                    const float4 a1 = *reinterpret_cast<const float4*>(&xs[tr + 16][dl]);
                    const int lb = q << 2;
#pragma unroll
                    for (int j2 = 0; j2 < 2; ++j2) {
                        const float4 b = *reinterpret_cast<const float4*>(&es[cbase + 16 * j2][el]);
                        acc[0][j2][lb + 0] = __builtin_fmaf(a0.x, b.x, acc[0][j2][lb + 0]);
                        acc[0][j2][lb + 1] = __builtin_fmaf(a0.y, b.y, acc[0][j2][lb + 1]);
                        acc[0][j2][lb + 2] = __builtin_fmaf(a0.z, b.z, acc[0][j2][lb + 2]);
                        acc[0][j2][lb + 3] = __builtin_fmaf(a0.w, b.w, acc[0][j2][lb + 3]);
                        acc[1][j2][lb + 0] = __builtin_fmaf(a1.x, b.x, acc[1][j2][lb + 0]);
                        acc[1][j2][lb + 1] = __builtin_fmaf(a1.y, b.y, acc[1][j2][lb + 1]);
                        acc[1][j2][lb + 2] = __builtin_fmaf(a1.z, b.z, acc[1][j2][lb + 2]);
                        acc[1][j2][lb + 3] = __builtin_fmaf(a1.w, b.w, acc[1][j2][lb + 3]);
                    }
                }
            }
        }
#pragma unroll
        for (int j2 = 0; j2 < 2; ++j2) {
            const int kk = k0 + cbase + 16 * j2;
            const float eq = esq[kk];
            {
                const float dist = __fadd_rn(__fsub_rn(xq0, __fmul_rn(2.0f, hsum16_np(acc[0][j2]))), eq);
                const u64 kkey = packkey(dist, (u32)kk);
                best0 = kkey < best0 ? kkey : best0;
            }
            {
                const float dist = __fadd_rn(__fsub_rn(xq1, __fmul_rn(2.0f, hsum16_np(acc[1][j2]))), eq);
                const u64 kkey = packkey(dist, (u32)kk);
                best1 = kkey < best1 ? kkey : best1;
            }
        }
    }
    __syncthreads();
    red[tr * 32 + (g << 4) + tc] = best0;
    red[(tr + 16) * 32 + (g << 4) + tc] = best1;
    __syncthreads();
    if (tid < 32) {
        u64 m = red[tid * 32];
#pragma unroll
        for (int t = 1; t < 32; ++t) {
            u64 v = red[tid * 32 + t];
            m = v < m ? v : m;
        }
        out_idx[n0 + tid] = (int)(m & 0xFFFFFFFFu);
    }
}

// ---------------- atomic-free scatter pipeline ----------------
__global__ void k_scan(const u32* __restrict__ hist, u32* __restrict__ offs) {
    __shared__ u32 ts[1024];
    const int t = threadIdx.x;
    const u32 h0 = hist[t * 4], h1 = hist[t * 4 + 1], h2 = hist[t * 4 + 2], h3 = hist[t * 4 + 3];
    const u32 tot = h0 + h1 + h2 + h3;
    ts[t] = tot;
    __syncthreads();
    for (int o = 1; o < 1024; o <<= 1) {
        const u32 add = (t >= o) ? ts[t - o] : 0u;
        __syncthreads();
        ts[t] += add;
        __syncthreads();
    }
    const u32 excl = ts[t] - tot;
    offs[t * 4] = excl;
    offs[t * 4 + 1] = excl + h0;
    offs[t * 4 + 2] = excl + h0 + h1;
    offs[t * 4 + 3] = excl + h0 + h1 + h2;
}

__global__ void k_place(const int* __restrict__ idx, u32* __restrict__ cursor,
                        const u32* __restrict__ offs, u32* __restrict__ rlist) {
    const int n = blockIdx.x * 256 + threadIdx.x;
    const int k = idx[n];
    const u32 p = atomicAdd(&cursor[k], 1u);
    rlist[offs[k] + p] = (u32)n;
}

__global__ void k_esum(const float* __restrict__ x, const u32* __restrict__ rlist,
                       const u32* __restrict__ offs, const u32* __restrict__ hist,
                       float* __restrict__ esum) {
    const int k = blockIdx.x;
    const int d = threadIdx.x;
    const u32 o = offs[k], c = hist[k];
    float s = 0.0f;
    for (u32 i = 0; i < c; ++i) s += x[((size_t)rlist[o + i] << 8) + d];
    esum[((size_t)k << 8) + d] = s;
}

__global__ void k_outloss(const float* __restrict__ x, const float* __restrict__ e,
                          const int* __restrict__ idx, float* __restrict__ out,
                          float* __restrict__ lpart) {
    const int d = threadIdx.x;
    float ls = 0.0f;
#pragma unroll
    for (int r = 0; r < 8; ++r) {
        const int n = blockIdx.x * 8 + r;
        const int k = idx[n];
        const size_t xi = ((size_t)n << 8) + d;
        const float xv = x[xi];
        const float qv = e[((size_t)k << 8) + d];
        const float diff = __fsub_rn(qv, xv);
        out[xi] = __fadd_rn(xv, diff);
        ls = __builtin_fmaf(diff, diff, ls);
    }
    __shared__ float sred[256];
    sred[d] = ls;
    __syncthreads();
    for (int s = 128; s > 0; s >>= 1) {
        if (d < s) sred[d] += sred[d + s];
        __syncthreads();
    }
    if (d == 0) lpart[blockIdx.x] = sred[0];
}

__global__ void k_cluster(const float* __restrict__ cs, const u32* __restrict__ hist,
                          float* __restrict__ ncs_out, float* __restrict__ n_out) {
    __shared__ float sred[1024];
    const int t = threadIdx.x;
    float s = 0.0f;
    for (int k = t; k < KCODES; k += 1024) {
        const float ncs = __fadd_rn(__fmul_rn(cs[k], 0.1f), __fmul_rn((float)hist[k], 0.9f));
        ncs_out[k] = ncs;
        s += ncs;
    }
    sred[t] = s;
    __syncthreads();
    for (int w = 512; w > 0; w >>= 1) {
        if (t < w) sred[t] += sred[t + w];
        __syncthreads();
    }
    if (t == 0) n_out[0] = sred[0];
}

__global__ void k_norm(const float* __restrict__ ea, const float* __restrict__ esum,
                       const float* __restrict__ ncs, const float* __restrict__ nptr,
                       float* __restrict__ en_out) {
    const int i = blockIdx.x * 256 + threadIdx.x;
    const int k = i >> 8;
    const float n = nptr[0];
    const float ncsk = ncs[k];
    const float smoothed = (ncsk + 1e-5f) / (n + 4096.0f * 1e-5f) * n;
    const float nea = __fadd_rn(__fmul_rn(ea[i], 0.1f), __fmul_rn(esum[i], 0.9f));
    en_out[i] = nea / smoothed;
}

__global__ void k_loss(const float* __restrict__ lpart, float* __restrict__ dst) {
    __shared__ float s[256];
    const int t = threadIdx.x;
    float a = 0.0f;
    for (int i = t; i < 4096; i += 256) a += lpart[i];
    s[t] = a;
    __syncthreads();
    for (int w = 128; w > 0; w >>= 1) {
        if (t < w) s[t] += s[t + w];
        __syncthreads();
    }
    if (t == 0) dst[0] = s[0] * (1.0f / 8388608.0f);
}

extern "C" void kernel_launch(void* const* d_in, const int* in_sizes, int n_in, void* d_out,
                              int out_size, void* d_ws, size_t ws_size, hipStream_t stream) {
    (void)in_sizes; (void)n_in; (void)out_size;
    const float* x = (const float*)d_in[0];
    const float* emb = (const float*)d_in[1];
    const float* cs = (const float*)d_in[2];
    const float* ea = (const float*)d_in[3];
    float* ws = (float*)d_ws;
    float* out = (float*)d_out;

    u32* w_cnt = (u32*)(ws + WS_CNT);
    float* w_emax = ws + WS_EMAX;
    u32* w_dis = (u32*)(ws + WS_DISTRUST);
    float* w_n = ws + WS_NSC;
    u32* w_hist = (u32*)(ws + WS_HIST);
    u32* w_offs = (u32*)(ws + WS_OFFS);
    u32* w_cursor = (u32*)(ws + WS_CURSOR);
    float* w_lpart = ws + WS_LPART;
    u32* w_rlist = (u32*)(ws + WS_RLIST);
    float* w_esum = ws + WS_ESUM;
    float* w_xsq = ws + WS_XSQ;
    float* w_esq = ws + WS_ESQ;
    int* w_idx = (int*)(ws + WS_IDX);
    u64* w_key = (u64*)(ws + WS_KEY);
    u64* w_tkey = (u64*)(ws + WS_TKEY);
    float* w_tm2 = ws + WS_TM2;
    u32* w_list = (u32*)(ws + WS_LIST);
    ushort* eh_g = (ushort*)(ws + WS_EH);
    ushort* el_g = (ushort*)(ws + WS_EL);

    float* o_out = out;              // [N*D]
    float* o_loss = out + 8388608;   // [1]
    float* o_ind = out + 8388609;    // [N]
    float* o_ncs = out + 8421377;    // [K]
    float* o_en = out + 8425473;     // [K*D]

    // x bf16-split packs live in the o_out region until k_outloss overwrites it
    ushort* xh_g = (ushort*)o_out;
    ushort* xl_g = (ushort*)o_out + 8388608;

    hipMemsetAsync(d_ws, 0, (size_t)WS_ZERO_FLOATS * sizeof(float), stream);

    k_rownorm<<<NROWS / 256, 256, 0, stream>>>(x, w_xsq, NROWS);
    k_rownorm<<<KCODES / 256, 256, 0, stream>>>(emb, w_esq, KCODES);

    if (ws_size >= (size_t)WS_TOTAL * sizeof(float)) {
        k_emax<<<1, 1024, 0, stream>>>(w_esq, w_emax);
        k_pack<<<4096, 256, 0, stream>>>(x, xh_g, xl_g);
        k_pack<<<512, 256, 0, stream>>>(emb, eh_g, el_g);
        k_mfma<<<dim3(128, 8), 512, 0, stream>>>(xh_g, xl_g, eh_g, el_g, w_xsq, w_esq,
                                                 w_tkey, w_tm2);
        k_merge<<<128, 256, 0, stream>>>(w_tkey, w_tm2, w_xsq, w_emax, w_key, w_list, w_cnt);
        k_verify<<<2048, 256, 0, stream>>>(x, emb, w_xsq, w_esq, w_emax, w_key, w_list,
                                           w_cnt, w_dis);
        k_distrust<<<128, 256, 0, stream>>>(w_dis, w_key, w_list, w_cnt);
        k_exact<<<8192, 512, 0, stream>>>(x, emb, w_xsq, w_esq, w_list, w_cnt, w_key);
        k_finhist<<<128, 256, 0, stream>>>(w_key, w_idx, w_hist, o_ind);
    } else {
        k_argmin_full<<<NROWS / 32, 512, 0, stream>>>(x, emb, w_xsq, w_esq, w_idx);
        k_finhist<<<128, 256, 0, stream>>>((u64*)w_key, w_idx, w_hist, o_ind);  // unreachable path guard
    }

    // atomic-free scatter pipeline
    k_scan<<<1, 1024, 0, stream>>>(w_hist, w_offs);
    k_place<<<128, 256, 0, stream>>>(w_idx, w_cursor, w_offs, w_rlist);
    k_esum<<<KCODES, 256, 0, stream>>>(x, w_rlist, w_offs, w_hist, w_esum);
    k_outloss<<<NROWS / 8, 256, 0, stream>>>(x, emb, w_idx, o_out, w_lpart);
    k_cluster<<<1, 1024, 0, stream>>>(cs, w_hist, o_ncs, w_n);
    k_norm<<<(KCODES * DDIM) / 256, 256, 0, stream>>>(ea, w_esum, o_ncs, w_n, o_en);
    k_loss<<<1, 256, 0, stream>>>(w_lpart, o_loss);
}

// Round 11
// 432.790 us; speedup vs baseline: 6.0578x; 1.0372x over previous
//
#include <hip/hip_runtime.h>
#include <hip/hip_bf16.h>
#include <cstdint>
#include <cstddef>

#define NROWS 32768
#define DDIM 256
#define KCODES 4096

typedef __attribute__((ext_vector_type(8))) short s16x8;
typedef __attribute__((ext_vector_type(4))) float f32x4;
typedef unsigned long long u64;
typedef unsigned int u32;

// ---------------- ws layout (float offsets), all 16B-aligned blocks ----------
#define WS_LOSS 0
#define WS_CNT 1
#define WS_EMAX 2
#define WS_DISTRUST 3
#define WS_NSC 4
#define WS_HIST 8                      // u32[4096]
#define WS_OFFS 4104                   // u32[4096]
#define WS_CURSOR 8200                 // u32[4096]
#define WS_LPART 12296                 // f32[4096]
#define WS_RLIST 16392                 // u32[32768]
#define WS_ESUM 49160                  // f32[1048576]
#define WS_XSQ 1097736                 // f32[32768]
#define WS_ESQ 1130504                 // f32[4096]
#define WS_IDX 1134600                 // i32[32768]
#define WS_KEY 1167368                 // u64[32768]
#define WS_TKEY 1232904                // u64[8*32768]
#define WS_TM2 1757192                 // f32[8*32768]
#define WS_LIST 2019336                // u32[32768]
#define WS_EH 2052104                  // ushort[1048576]
#define WS_EL 2576392                  // ushort[1048576]
#define WS_TOTAL 3100680
#define WS_ZERO_FLOATS 12296           // header + hist + offs + cursor

__device__ __forceinline__ float hsum16_np(const float a[16]) {
    float t3[8];
#pragma unroll
    for (int m = 0; m < 8; ++m) t3[m] = __fadd_rn(a[m + 8], a[m]);
    float t6[4];
#pragma unroll
    for (int m = 0; m < 4; ++m) t6[m] = __fadd_rn(t3[m + 4], t3[m]);
    return __fadd_rn(__fadd_rn(t6[0], t6[2]), __fadd_rn(t6[1], t6[3]));
}

__device__ __forceinline__ float np_sum_sq_128(const float* a) {
    float t[16];
#pragma unroll
    for (int l = 0; l < 16; ++l) {
        float m0 = __fmul_rn(a[l], a[l]);
        float m1 = __fmul_rn(a[16 + l], a[16 + l]);
        float m2 = __fmul_rn(a[32 + l], a[32 + l]);
        float m3 = __fmul_rn(a[48 + l], a[48 + l]);
        float m4 = __fmul_rn(a[64 + l], a[64 + l]);
        float m5 = __fmul_rn(a[80 + l], a[80 + l]);
        float m6 = __fmul_rn(a[96 + l], a[96 + l]);
        float m7 = __fmul_rn(a[112 + l], a[112 + l]);
        float s01 = __fadd_rn(m0, m1);
        float s23 = __fadd_rn(m2, m3);
        float s45 = __fadd_rn(m4, m5);
        float s67 = __fadd_rn(m6, m7);
        t[l] = __fadd_rn(__fadd_rn(s01, s23), __fadd_rn(s45, s67));
    }
    return hsum16_np(t);
}

__global__ void k_rownorm(const float* __restrict__ src, float* __restrict__ dst, int rows) {
    int r = blockIdx.x * blockDim.x + threadIdx.x;
    if (r < rows) {
        const float* p = src + ((size_t)r << 8);
        dst[r] = __fadd_rn(np_sum_sq_128(p), np_sum_sq_128(p + 128));
    }
}

__global__ void k_emax(const float* __restrict__ esq, float* __restrict__ emax) {
    __shared__ float s[1024];
    int t = threadIdx.x;
    float m = 0.0f;
    for (int i = t; i < KCODES; i += 1024) m = fmaxf(m, esq[i]);
    s[t] = m;
    __syncthreads();
    for (int w = 512; w > 0; w >>= 1) {
        if (t < w) s[t] = fmaxf(s[t], s[t + w]);
        __syncthreads();
    }
    if (t == 0) emax[0] = s[0];
}

// RNE bf16 from fp32 bits (normal values only here)
__device__ __forceinline__ ushort bf16_rn(float x) {
    u32 u = __float_as_uint(x);
    u32 r = (u + 0x7fffu + ((u >> 16) & 1u)) >> 16;
    return (ushort)r;
}
__device__ __forceinline__ float bf16_f(ushort h) { return __uint_as_float(((u32)h) << 16); }

__global__ void k_pack(const float* __restrict__ src, ushort* __restrict__ hi,
                       ushort* __restrict__ lo) {
    int i = (blockIdx.x * 256 + threadIdx.x) * 8;
    float4 v0 = *reinterpret_cast<const float4*>(src + i);
    float4 v1 = *reinterpret_cast<const float4*>(src + i + 4);
    float f[8] = {v0.x, v0.y, v0.z, v0.w, v1.x, v1.y, v1.z, v1.w};
    ushort h[8], l[8];
#pragma unroll
    for (int j = 0; j < 8; ++j) {
        h[j] = bf16_rn(f[j]);
        l[j] = bf16_rn(__fsub_rn(f[j], bf16_f(h[j])));
    }
    *reinterpret_cast<s16x8*>(hi + i) = *reinterpret_cast<s16x8*>(h);
    *reinterpret_cast<s16x8*>(lo + i) = *reinterpret_cast<s16x8*>(l);
}

__device__ __forceinline__ float keyval_(u64 k) {
    u32 u = (u32)(k >> 32);
    u = (u & 0x80000000u) ? (u ^ 0x80000000u) : ~u;
    return __uint_as_float(u);
}
__device__ __forceinline__ u64 packkey(float d, u32 j) {
    u32 u = __float_as_uint(d);
    u ^= (u32)((int)u >> 31) | 0x80000000u;
    return ((u64)u << 32) | j;
}
#define KEY_INIT 0xFF8000007FFFFFFFull  // packkey(+INF, 0x7fffffff)

__device__ __forceinline__ void dma16(const void* g, void* l) {
    __builtin_amdgcn_global_load_lds(
        (const __attribute__((address_space(1))) void*)g,
        (__attribute__((address_space(3))) void*)l, 16, 0, 0);
}

// one (c,ks) sub-step: read 4 b-frags from e LDS, 24 MFMAs into acc.
// Sequence per (q): ns0{hh,hl,lh}, ns1{hh,hl,lh} — identical to R8/R9.
__device__ __forceinline__ void ckstep(const char* eh, const char* el, int coff, int o,
                                       int lr, s16x8 fh0, s16x8 fh1, s16x8 fl0, s16x8 fl1,
                                       f32x4 acc[2][4]) {
#pragma unroll
    for (int jp = 0; jp < 2; ++jp) {
        s16x8 beh[2], bel[2];
#pragma unroll
        for (int q = 0; q < 2; ++q) {
            const int rowb = (((jp * 2 + q) * 16 + lr) << 9) + coff + o;
            beh[q] = *(const s16x8*)(eh + rowb);
            bel[q] = *(const s16x8*)(el + rowb);
        }
#pragma unroll
        for (int q = 0; q < 2; ++q) {
            const int jsub = jp * 2 + q;
            acc[0][jsub] = __builtin_amdgcn_mfma_f32_16x16x32_bf16(fh0, beh[q], acc[0][jsub], 0, 0, 0);
            acc[0][jsub] = __builtin_amdgcn_mfma_f32_16x16x32_bf16(fh0, bel[q], acc[0][jsub], 0, 0, 0);
            acc[0][jsub] = __builtin_amdgcn_mfma_f32_16x16x32_bf16(fl0, beh[q], acc[0][jsub], 0, 0, 0);
            acc[1][jsub] = __builtin_amdgcn_mfma_f32_16x16x32_bf16(fh1, beh[q], acc[1][jsub], 0, 0, 0);
            acc[1][jsub] = __builtin_amdgcn_mfma_f32_16x16x32_bf16(fh1, bel[q], acc[1][jsub], 0, 0, 0);
            acc[1][jsub] = __builtin_amdgcn_mfma_f32_16x16x32_bf16(fl1, beh[q], acc[1][jsub], 0, 0, 0);
        }
    }
}

// R10 k_mfma: 512 thr (8 waves), tile 256n x 512j, grid 128x8.
// x held in REGISTERS (32 s16x8 frags/thread, static-indexed) loaded once via a
// 4-chunk LDS staging prologue; js loop streams ONLY e (64KB/phase) through a
// 2x64KB LDS double buffer with issue-early DMA + ONE barrier per phase (the
// per-wave vmcnt(0) inside __syncthreads drains DMA that had a full compute
// phase of head start). DMA bytes 2.6GB -> 1.34GB vs R9; a-side LDS reads gone.
// 128KB LDS caps the CU at 1 block = 8 waves = 2/SIMD, which structurally pins
// the 256-VGPR budget (working set ~230) — no allocator bucket-chasing possible.
// Per-(n,j) MFMA/epilogue sequence bit-identical to R8/R9.
__global__ __attribute__((amdgpu_flat_work_group_size(512, 512), amdgpu_waves_per_eu(2, 2)))
void k_mfma(const ushort* __restrict__ xh_g, const ushort* __restrict__ xl_g,
            const ushort* __restrict__ eh_g, const ushort* __restrict__ el_g,
            const float* __restrict__ xsq, const float* __restrict__ esq,
            u64* __restrict__ tkey, float* __restrict__ tm2) {
    __shared__ __align__(16) char lds[131072];  // buf0 @0, buf1 @65536; h @+0, l @+32768

    const int tid = threadIdx.x;
    const int w = tid >> 6, l = tid & 63, lr = l & 15, lg = l >> 4;
    const int n0 = blockIdx.x * 256, jb = blockIdx.y, j0 = jb * 512;
    const int key = (lr & 7) << 4;
    const int o0 = (lg * 16) ^ key;
    const int o1 = (64 + lg * 16) ^ key;

    // ---- prologue: stage x chunks through alternating buffers, read frags ----
    s16x8 fh[4][2][2], fl[4][2][2];  // [c][ks][ns] — all indices static after unroll
    {
        // issue chunk 0 -> buf0
#pragma unroll
        for (int p = 0; p < 4; ++p) {
            int m = tid + p * 512, r = m >> 3, cb = (m & 7) << 4;
            size_t so = (size_t)(n0 + r) * 256 + 0 * 64 + ((cb ^ ((r & 7) << 4)) >> 1);
            dma16(xh_g + so, lds + m * 16);
            dma16(xl_g + so, lds + 32768 + m * 16);
        }
        __syncthreads();  // chunk0 drained
#pragma unroll
        for (int c = 0; c < 4; ++c) {
            const char* xa = lds + ((c & 1) << 16);
            // issue next chunk into the other buffer (overlaps frag reads)
            if (c < 3) {
                char* xb = lds + (((c + 1) & 1) << 16);
#pragma unroll
                for (int p = 0; p < 4; ++p) {
                    int m = tid + p * 512, r = m >> 3, cb = (m & 7) << 4;
                    size_t so = (size_t)(n0 + r) * 256 + (c + 1) * 64 + ((cb ^ ((r & 7) << 4)) >> 1);
                    dma16(xh_g + so, xb + m * 16);
                    dma16(xl_g + so, xb + 32768 + m * 16);
                }
            }
#pragma unroll
            for (int ks = 0; ks < 2; ++ks)
#pragma unroll
                for (int ns = 0; ns < 2; ++ns) {
                    const int addr = ((w * 32 + ns * 16 + lr) << 7) + (ks ? o1 : o0);
                    fh[c][ks][ns] = *(const s16x8*)(xa + addr);
                    fl[c][ks][ns] = *(const s16x8*)(xa + 32768 + addr);
                }
            __syncthreads();  // frag reads done; next chunk drained
        }
        // issue e[js=0] -> buf0 (x frag reads from buf0 finished at c=2 barrier)
#pragma unroll
        for (int p = 0; p < 4; ++p) {
            int m = tid + p * 512, r = m >> 5, cb = (m & 31) << 4;
            int scol = (cb & ~127) | ((cb & 127) ^ ((r & 7) << 4));
            size_t so = (size_t)(j0 + r) * 256 + (scol >> 1);
            dma16(eh_g + so, lds + m * 16);
            dma16(el_g + so, lds + 32768 + m * 16);
        }
        __syncthreads();  // e[0] drained
    }

    float xq[8];
#pragma unroll
    for (int i = 0; i < 8; ++i)
        xq[i] = xsq[n0 + w * 32 + (i >> 2) * 16 + lg * 4 + (i & 3)];

    u64 K1[8];
    float M2[8];
#pragma unroll
    for (int i = 0; i < 8; ++i) { K1[i] = KEY_INIT; M2[i] = __uint_as_float(0x7F800000u); }

    // ---- main loop: 8 e-phases, one barrier each ----
    for (int js = 0; js < 8; ++js) {
        const int jbase = j0 + js * 64;
        const char* eh = lds + ((js & 1) << 16);
        const char* el = eh + 32768;
        // issue-early: DMA e[js+1] into the other buffer (its readers finished
        // before the barrier we just passed)
        if (js < 7) {
            char* nh = lds + (((js + 1) & 1) << 16);
#pragma unroll
            for (int p = 0; p < 4; ++p) {
                int m = tid + p * 512, r = m >> 5, cb = (m & 31) << 4;
                int scol = (cb & ~127) | ((cb & 127) ^ ((r & 7) << 4));
                size_t so = (size_t)(jbase + 64 + r) * 256 + (scol >> 1);
                dma16(eh_g + so, nh + m * 16);
                dma16(el_g + so, nh + 32768 + m * 16);
            }
        }

        f32x4 acc[2][4];
#pragma unroll
        for (int a = 0; a < 2; ++a)
#pragma unroll
            for (int b = 0; b < 4; ++b) acc[a][b] = (f32x4){0.f, 0.f, 0.f, 0.f};

#pragma unroll
        for (int c = 0; c < 4; ++c) {
            ckstep(eh, el, c * 128, o0, lr, fh[c][0][0], fh[c][0][1], fl[c][0][0], fl[c][0][1], acc);
            ckstep(eh, el, c * 128, o1, lr, fh[c][1][0], fh[c][1][1], fl[c][1][0], fl[c][1][1], acc);
        }

        // epilogue for this js: d~ with the exact final-op sequence
#pragma unroll
        for (int jsub = 0; jsub < 4; ++jsub) {
            const int j = jbase + jsub * 16 + lr;
            const float eq = esq[j];
#pragma unroll
            for (int ns = 0; ns < 2; ++ns)
#pragma unroll
                for (int r = 0; r < 4; ++r) {
                    const float s = acc[ns][jsub][r];
                    const float d = __fadd_rn(__fsub_rn(xq[ns * 4 + r], __fmul_rn(2.0f, s)), eq);
                    const u64 kk = packkey(d, (u32)j);
                    const int i8 = ns * 4 + r;
                    if (kk < K1[i8]) { M2[i8] = keyval_(K1[i8]); K1[i8] = kk; }
                    else if (d < M2[i8]) M2[i8] = d;
                }
        }
        __syncthreads();  // drains own e[js+1] DMA (head start = whole compute)
    }

    // cross-lane merge over the 16 j-lanes (masks stay in-group)
#pragma unroll
    for (int i8 = 0; i8 < 8; ++i8) {
        u64 k1 = K1[i8];
        float m2 = M2[i8];
#pragma unroll
        for (int mk = 1; mk < 16; mk <<= 1) {
            u32 klo = __shfl_xor((u32)k1, mk);
            u32 khi = __shfl_xor((u32)(k1 >> 32), mk);
            float om2 = __shfl_xor(m2, mk);
            u64 ok = ((u64)khi << 32) | klo;
            if (ok < k1) { m2 = fminf(om2, keyval_(k1)); k1 = ok; }
            else m2 = fminf(m2, keyval_(ok));
        }
        if (lr == 0) {
            const int n = n0 + w * 32 + (i8 >> 2) * 16 + lg * 4 + (i8 & 3);
            tkey[(size_t)jb * NROWS + n] = k1;
            tm2[(size_t)jb * NROWS + n] = m2;
        }
    }
}

__global__ void k_merge(const u64* __restrict__ tkey, const float* __restrict__ tm2,
                        const float* __restrict__ xsq, const float* __restrict__ emaxp,
                        u64* __restrict__ key64, u32* __restrict__ list, u32* __restrict__ cnt) {
    const int n = blockIdx.x * 256 + threadIdx.x;
    u64 k1 = tkey[n];
    float m2 = tm2[n];
#pragma unroll
    for (int jb = 1; jb < 8; ++jb) {
        u64 ok = tkey[(size_t)jb * NROWS + n];
        float om2 = tm2[(size_t)jb * NROWS + n];
        if (ok < k1) { m2 = fminf(om2, keyval_(k1)); k1 = ok; }
        else m2 = fminf(m2, keyval_(ok));
    }
    const float B = sqrtf(xsq[n] * emaxp[0]);
    const float Ed = 2.4e-4f * B + 1.5e-4f;
    if (m2 - keyval_(k1) <= 2.0f * Ed) {
        key64[n] = ~0ull;
        list[atomicAdd(cnt, 1u)] = (u32)n;
    } else {
        key64[n] = k1;
    }
}

// exact numpy-order dist(n, approx-winner) vs d~(winner): bound-slip / layout guard
__global__ void k_verify(const float* __restrict__ x, const float* __restrict__ e,
                         const float* __restrict__ xsq, const float* __restrict__ esq,
                         const float* __restrict__ emaxp, u64* __restrict__ key64,
                         u32* __restrict__ list, u32* __restrict__ cnt,
                         u32* __restrict__ distrust) {
    const int li = threadIdx.x & 15;
    const int n = blockIdx.x * 16 + (threadIdx.x >> 4);
    const u64 k = key64[n];
    const bool active = (k != ~0ull);
    const int idx = active ? (int)(k & 0xFFFu) : 0;
    const float* xr = x + ((size_t)n << 8);
    const float* er = e + ((size_t)idx << 8);
    float a = 0.0f;
#pragma unroll
    for (int g = 0; g < 4; ++g)
#pragma unroll
        for (int bb = 3; bb >= 0; --bb) {
            const int d = (g * 4 + bb) * 16 + li;
            a = __builtin_fmaf(xr[d], er[d], a);
        }
    const float s1 = __fadd_rn(__shfl_xor(a, 8), a);
    const float s2 = __fadd_rn(__shfl_xor(s1, 4), s1);
    const float u = __fadd_rn(s2, __shfl_xor(s2, 2));
    const float dot = __fadd_rn(u, __shfl_xor(u, 1));
    if (li == 0 && active) {
        const float d = __fadd_rn(__fsub_rn(xsq[n], __fmul_rn(2.0f, dot)), esq[idx]);
        const float dref = keyval_(k);
        const float B = sqrtf(xsq[n] * emaxp[0]);
        const float Ed = 2.4e-4f * B + 1.5e-4f;
        const float diff = fabsf(d - dref);
        if (diff > Ed) {
            key64[n] = ~0ull;
            list[atomicAdd(cnt, 1u)] = (u32)n;
            if (diff > 0.05f) atomicOr(distrust, 1u);
        }
    }
}

__global__ void k_distrust(const u32* __restrict__ distrust, u64* __restrict__ key64,
                           u32* __restrict__ list, u32* __restrict__ cnt) {
    if (*distrust == 0u) return;
    const int n = blockIdx.x * 256 + threadIdx.x;
    key64[n] = ~0ull;
    list[n] = (u32)n;
    if (n == 0) *cnt = (u32)NROWS;
}

// exact numpy-order argmin over a 512-k segment for 32 flagged rows
__global__ __attribute__((amdgpu_flat_work_group_size(512, 512), amdgpu_waves_per_eu(4)))
void k_exact(const float* __restrict__ x, const float* __restrict__ embed,
             const float* __restrict__ xsq, const float* __restrict__ esq,
             const u32* __restrict__ list, const u32* __restrict__ cntp,
             u64* __restrict__ key64) {
    const u32 cnt = *cntp;
    const int grp = blockIdx.x >> 3, seg = blockIdx.x & 7;
    const u32 base = (u32)grp * 32u;
    if (base >= cnt) return;

    __shared__ float xs[32][260];
    __shared__ float es[64][68];
    u64* red = (u64*)&es[0][0];

    const int tid = threadIdx.x;
    const int lane = tid & 63;
    const int w = tid >> 6;
    const int g = w >> 2;
    const int tc = lane & 15;
    const int tr = ((w & 3) << 2) + (lane >> 4);
    const int cbase = (g << 5) + tc;

#pragma unroll
    for (int p = 0; p < 4; ++p) {
        int v = tid + p * 512;
        int r = v >> 6;
        int c4 = (v & 63) << 2;
        u32 row = list[(base + (u32)r < cnt) ? base + r : base];
        const float4 f = *reinterpret_cast<const float4*>(x + ((size_t)row << 8) + c4);
        *reinterpret_cast<float4*>(&xs[r][c4]) = f;
    }

    const u32 row0 = list[(base + (u32)tr < cnt) ? base + tr : base];
    const u32 row1 = list[(base + (u32)tr + 16u < cnt) ? base + tr + 16 : base];
    const float xq0 = xsq[row0];
    const float xq1 = xsq[row1];

    u64 best0 = ~0ull, best1 = ~0ull;

    for (int ktl = 0; ktl < 8; ++ktl) {
        const int k0 = seg * 512 + ktl * 64;
        float acc[2][2][16];
#pragma unroll
        for (int i = 0; i < 2; ++i)
#pragma unroll
            for (int j = 0; j < 2; ++j)
#pragma unroll
                for (int q = 0; q < 16; ++q) acc[i][j][q] = 0.0f;

        for (int c = 0; c < 4; ++c) {
            __syncthreads();
#pragma unroll
            for (int p = 0; p < 2; ++p) {
                int v = tid + p * 512;
                int r = v >> 4;
                int c4 = (v & 15) << 2;
                const float4 f = *reinterpret_cast<const float4*>(
                    embed + ((size_t)(k0 + r) << 8) + (c << 6) + c4);
                *reinterpret_cast<float4*>(&es[r][c4]) = f;
            }
            __syncthreads();
#pragma unroll
            for (int jj = 3; jj >= 0; --jj) {
#pragma unroll
                for (int q = 0; q < 4; ++q) {
                    const int dl = ((c * 4 + jj) << 4) + (q << 2);
                    const int el = (jj << 4) + (q << 2);
                    const float4 a0 = *reinterpret_cast<const float4*>(&xs[tr][dl]);
                    const float4 a1 = *reinterpret_cast<const float4*>(&xs[tr + 16][dl]);
                    const int lb = q << 2;
#pragma unroll
                    for (int j2 = 0; j2 < 2; ++j2) {
                        const float4 b = *reinterpret_cast<const float4*>(&es[cbase + 16 * j2][el]);
                        acc[0][j2][lb + 0] = __builtin_fmaf(a0.x, b.x, acc[0][j2][lb + 0]);
                        acc[0][j2][lb + 1] = __builtin_fmaf(a0.y, b.y, acc[0][j2][lb + 1]);
                        acc[0][j2][lb + 2] = __builtin_fmaf(a0.z, b.z, acc[0][j2][lb + 2]);
                        acc[0][j2][lb + 3] = __builtin_fmaf(a0.w, b.w, acc[0][j2][lb + 3]);
                        acc[1][j2][lb + 0] = __builtin_fmaf(a1.x, b.x, acc[1][j2][lb + 0]);
                        acc[1][j2][lb + 1] = __builtin_fmaf(a1.y, b.y, acc[1][j2][lb + 1]);
                        acc[1][j2][lb + 2] = __builtin_fmaf(a1.z, b.z, acc[1][j2][lb + 2]);
                        acc[1][j2][lb + 3] = __builtin_fmaf(a1.w, b.w, acc[1][j2][lb + 3]);
                    }
                }
            }
        }
#pragma unroll
        for (int j2 = 0; j2 < 2; ++j2) {
            const int kk = k0 + cbase + 16 * j2;
            const float eq = esq[kk];
            {
                const float dist = __fadd_rn(__fsub_rn(xq0, __fmul_rn(2.0f, hsum16_np(acc[0][j2]))), eq);
                const u64 kkey = packkey(dist, (u32)kk);
                best0 = kkey < best0 ? kkey : best0;
            }
            {
                const float dist = __fadd_rn(__fsub_rn(xq1, __fmul_rn(2.0f, hsum16_np(acc[1][j2]))), eq);
                const u64 kkey = packkey(dist, (u32)kk);
                best1 = kkey < best1 ? kkey : best1;
            }
        }
    }

    __syncthreads();
    red[tr * 32 + (g << 4) + tc] = best0;
    red[(tr + 16) * 32 + (g << 4) + tc] = best1;
    __syncthreads();
    if (tid < 32) {
        u64 m = red[tid * 32];
#pragma unroll
        for (int t = 1; t < 32; ++t) {
            u64 v = red[tid * 32 + t];
            m = v < m ? v : m;
        }
        if (base + (u32)tid < cnt) atomicMin(&key64[list[base + tid]], m);
    }
}

// finalize idx + histogram + ind_out in one pass
__global__ void k_finhist(const u64* __restrict__ key64, int* __restrict__ idx,
                          u32* __restrict__ hist, float* __restrict__ ind_out) {
    const int n = blockIdx.x * 256 + threadIdx.x;
    const int k = (int)(key64[n] & 0xFFFull);
    idx[n] = k;
    atomicAdd(&hist[k], 1u);
    ind_out[n] = (float)k;
}

// fallback-path hist (reads idx directly)
__global__ void k_histidx(const int* __restrict__ idx, u32* __restrict__ hist,
                          float* __restrict__ ind_out) {
    const int n = blockIdx.x * 256 + threadIdx.x;
    const int k = idx[n];
    atomicAdd(&hist[k], 1u);
    ind_out[n] = (float)k;
}

// ---------- fallback full-exact argmin (R6 kernel, known-good) ----------
__global__ __attribute__((amdgpu_flat_work_group_size(512, 512), amdgpu_waves_per_eu(4)))
void k_argmin_full(const float* __restrict__ x, const float* __restrict__ embed,
                   const float* __restrict__ xsq, const float* __restrict__ esq,
                   int* __restrict__ out_idx) {
    __shared__ float xs[32][260];
    __shared__ float es[64][68];
    u64* red = (u64*)&es[0][0];
    const int tid = threadIdx.x;
    const int lane = tid & 63;
    const int w = tid >> 6;
    const int g = w >> 2;
    const int tc = lane & 15;
    const int tr = ((w & 3) << 2) + (lane >> 4);
    const int cbase = (g << 5) + tc;
    const int n0 = blockIdx.x * 32;
#pragma unroll
    for (int p = 0; p < 4; ++p) {
        int v = tid + p * 512;
        int r = v >> 6;
        int c4 = (v & 63) << 2;
        const float4 f = *reinterpret_cast<const float4*>(x + ((size_t)(n0 + r) << 8) + c4);
        *reinterpret_cast<float4*>(&xs[r][c4]) = f;
    }
    const float xq0 = xsq[n0 + tr];
    const float xq1 = xsq[n0 + tr + 16];
    u64 best0 = ~0ull, best1 = ~0ull;
    for (int kt = 0; kt < KCODES / 64; ++kt) {
        const int k0 = kt * 64;
        float acc[2][2][16];
#pragma unroll
        for (int i = 0; i < 2; ++i)
#pragma unroll
            for (int j = 0; j < 2; ++j)
#pragma unroll
                for (int q = 0; q < 16; ++q) acc[i][j][q] = 0.0f;
        for (int c = 0; c < 4; ++c) {
            __syncthreads();
#pragma unroll
            for (int p = 0; p < 2; ++p) {
                int v = tid + p * 512;
                int r = v >> 4;
                int c4 = (v & 15) << 2;
                const float4 f = *reinterpret_cast<const float4*>(
                    embed + ((size_t)(k0 + r) << 8) + (c << 6) + c4);
                *reinterpret_cast<float4*>(&es[r][c4]) = f;
            }
            __syncthreads();
#pragma unroll
            for (int jj = 3; jj >= 0; --jj) {
#pragma unroll
                for (int q = 0; q < 4; ++q) {
                    const int dl = ((c * 4 + jj) << 4) + (q << 2);
                    const int el = (jj << 4) + (q << 2);
                    const float4 a0 = *reinterpret_cast<const float4*>(&xs[tr][dl]);
                    const float4 a1 = *reinterpret_cast<const float4*>(&xs[tr + 16][dl]);
                    const int lb = q << 2;
#pragma unroll
                    for (int j2 = 0; j2 < 2; ++j2) {
                        const float4 b = *reinterpret_cast<const float4*>(&es[cbase + 16 * j2][el]);
                        acc[0][j2][lb + 0] = __builtin_fmaf(a0.x, b.x, acc[0][j2][lb + 0]);
                        acc[0][j2][lb + 1] = __builtin_fmaf(a0.y, b.y, acc[0][j2][lb + 1]);
                        acc[0][j2][lb + 2] = __builtin_fmaf(a0.z, b.z, acc[0][j2][lb + 2]);
                        acc[0][j2][lb + 3] = __builtin_fmaf(a0.w, b.w, acc[0][j2][lb + 3]);
                        acc[1][j2][lb + 0] = __builtin_fmaf(a1.x, b.x, acc[1][j2][lb + 0]);
                        acc[1][j2][lb + 1] = __builtin_fmaf(a1.y, b.y, acc[1][j2][lb + 1]);
                        acc[1][j2][lb + 2] = __builtin_fmaf(a1.z, b.z, acc[1][j2][lb + 2]);
                        acc[1][j2][lb + 3] = __builtin_fmaf(a1.w, b.w, acc[1][j2][lb + 3]);
                    }
                }
            }
        }
#pragma unroll
        for (int j2 = 0; j2 < 2; ++j2) {
            const int kk = k0 + cbase + 16 * j2;
            const float eq = esq[kk];
            {
                const float dist = __fadd_rn(__fsub_rn(xq0, __fmul_rn(2.0f, hsum16_np(acc[0][j2]))), eq);
                const u64 kkey = packkey(dist, (u32)kk);
                best0 = kkey < best0 ? kkey : best0;
            }
            {
                const float dist = __fadd_rn(__fsub_rn(xq1, __fmul_rn(2.0f, hsum16_np(acc[1][j2]))), eq);
                const u64 kkey = packkey(dist, (u32)kk);
                best1 = kkey < best1 ? kkey : best1;
            }
        }
    }
    __syncthreads();
    red[tr * 32 + (g << 4) + tc] = best0;
    red[(tr + 16) * 32 + (g << 4) + tc] = best1;
    __syncthreads();
    if (tid < 32) {
        u64 m = red[tid * 32];
#pragma unroll
        for (int t = 1; t < 32; ++t) {
            u64 v = red[tid * 32 + t];
            m = v < m ? v : m;
        }
        out_idx[n0 + tid] = (int)(m & 0xFFFFFFFFu);
    }
}

// ---------------- atomic-free scatter pipeline ----------------
__global__ void k_scan(const u32* __restrict__ hist, u32* __restrict__ offs) {
    __shared__ u32 ts[1024];
    const int t = threadIdx.x;
    const u32 h0 = hist[t * 4], h1 = hist[t * 4 + 1], h2 = hist[t * 4 + 2], h3 = hist[t * 4 + 3];
    const u32 tot = h0 + h1 + h2 + h3;
    ts[t] = tot;
    __syncthreads();
    for (int o = 1; o < 1024; o <<= 1) {
        const u32 add = (t >= o) ? ts[t - o] : 0u;
        __syncthreads();
        ts[t] += add;
        __syncthreads();
    }
    const u32 excl = ts[t] - tot;
    offs[t * 4] = excl;
    offs[t * 4 + 1] = excl + h0;
    offs[t * 4 + 2] = excl + h0 + h1;
    offs[t * 4 + 3] = excl + h0 + h1 + h2;
}

__global__ void k_place(const int* __restrict__ idx, u32* __restrict__ cursor,
                        const u32* __restrict__ offs, u32* __restrict__ rlist) {
    const int n = blockIdx.x * 256 + threadIdx.x;
    const int k = idx[n];
    const u32 p = atomicAdd(&cursor[k], 1u);
    rlist[offs[k] + p] = (u32)n;
}

__global__ void k_esum(const float* __restrict__ x, const u32* __restrict__ rlist,
                       const u32* __restrict__ offs, const u32* __restrict__ hist,
                       float* __restrict__ esum) {
    const int k = blockIdx.x;
    const int d = threadIdx.x;
    const u32 o = offs[k], c = hist[k];
    float s = 0.0f;
    for (u32 i = 0; i < c; ++i) s += x[((size_t)rlist[o + i] << 8) + d];
    esum[((size_t)k << 8) + d] = s;
}

__global__ void k_outloss(const float* __restrict__ x, const float* __restrict__ e,
                          const int* __restrict__ idx, float* __restrict__ out,
                          float* __restrict__ lpart) {
    const int d = threadIdx.x;
    float ls = 0.0f;
#pragma unroll
    for (int r = 0; r < 8; ++r) {
        const int n = blockIdx.x * 8 + r;
        const int k = idx[n];
        const size_t xi = ((size_t)n << 8) + d;
        const float xv = x[xi];
        const float qv = e[((size_t)k << 8) + d];
        const float diff = __fsub_rn(qv, xv);
        out[xi] = __fadd_rn(xv, diff);
        ls = __builtin_fmaf(diff, diff, ls);
    }
    __shared__ float sred[256];
    sred[d] = ls;
    __syncthreads();
    for (int s = 128; s > 0; s >>= 1) {
        if (d < s) sred[d] += sred[d + s];
        __syncthreads();
    }
    if (d == 0) lpart[blockIdx.x] = sred[0];
}

__global__ void k_cluster(const float* __restrict__ cs, const u32* __restrict__ hist,
                          float* __restrict__ ncs_out, float* __restrict__ n_out) {
    __shared__ float sred[1024];
    const int t = threadIdx.x;
    float s = 0.0f;
    for (int k = t; k < KCODES; k += 1024) {
        const float ncs = __fadd_rn(__fmul_rn(cs[k], 0.1f), __fmul_rn((float)hist[k], 0.9f));
        ncs_out[k] = ncs;
        s += ncs;
    }
    sred[t] = s;
    __syncthreads();
    for (int w = 512; w > 0; w >>= 1) {
        if (t < w) sred[t] += sred[t + w];
        __syncthreads();
    }
    if (t == 0) n_out[0] = sred[0];
}

__global__ void k_norm(const float* __restrict__ ea, const float* __restrict__ esum,
                       const float* __restrict__ ncs, const float* __restrict__ nptr,
                       float* __restrict__ en_out) {
    const int i = blockIdx.x * 256 + threadIdx.x;
    const int k = i >> 8;
    const float n = nptr[0];
    const float ncsk = ncs[k];
    const float smoothed = (ncsk + 1e-5f) / (n + 4096.0f * 1e-5f) * n;
    const float nea = __fadd_rn(__fmul_rn(ea[i], 0.1f), __fmul_rn(esum[i], 0.9f));
    en_out[i] = nea / smoothed;
}

__global__ void k_loss(const float* __restrict__ lpart, float* __restrict__ dst) {
    __shared__ float s[256];
    const int t = threadIdx.x;
    float a = 0.0f;
    for (int i = t; i < 4096; i += 256) a += lpart[i];
    s[t] = a;
    __syncthreads();
    for (int w = 128; w > 0; w >>= 1) {
        if (t < w) s[t] += s[t + w];
        __syncthreads();
    }
    if (t == 0) dst[0] = s[0] * (1.0f / 8388608.0f);
}

extern "C" void kernel_launch(void* const* d_in, const int* in_sizes, int n_in, void* d_out,
                              int out_size, void* d_ws, size_t ws_size, hipStream_t stream) {
    (void)in_sizes; (void)n_in; (void)out_size;
    const float* x = (const float*)d_in[0];
    const float* emb = (const float*)d_in[1];
    const float* cs = (const float*)d_in[2];
    const float* ea = (const float*)d_in[3];
    float* ws = (float*)d_ws;
    float* out = (float*)d_out;

    u32* w_cnt = (u32*)(ws + WS_CNT);
    float* w_emax = ws + WS_EMAX;
    u32* w_dis = (u32*)(ws + WS_DISTRUST);
    float* w_n = ws + WS_NSC;
    u32* w_hist = (u32*)(ws + WS_HIST);
    u32* w_offs = (u32*)(ws + WS_OFFS);
    u32* w_cursor = (u32*)(ws + WS_CURSOR);
    float* w_lpart = ws + WS_LPART;
    u32* w_rlist = (u32*)(ws + WS_RLIST);
    float* w_esum = ws + WS_ESUM;
    float* w_xsq = ws + WS_XSQ;
    float* w_esq = ws + WS_ESQ;
    int* w_idx = (int*)(ws + WS_IDX);
    u64* w_key = (u64*)(ws + WS_KEY);
    u64* w_tkey = (u64*)(ws + WS_TKEY);
    float* w_tm2 = ws + WS_TM2;
    u32* w_list = (u32*)(ws + WS_LIST);
    ushort* eh_g = (ushort*)(ws + WS_EH);
    ushort* el_g = (ushort*)(ws + WS_EL);

    float* o_out = out;              // [N*D]
    float* o_loss = out + 8388608;   // [1]
    float* o_ind = out + 8388609;    // [N]
    float* o_ncs = out + 8421377;    // [K]
    float* o_en = out + 8425473;     // [K*D]

    // x bf16-split packs live in the o_out region until k_outloss overwrites it
    ushort* xh_g = (ushort*)o_out;
    ushort* xl_g = (ushort*)o_out + 8388608;

    hipMemsetAsync(d_ws, 0, (size_t)WS_ZERO_FLOATS * sizeof(float), stream);

    k_rownorm<<<NROWS / 256, 256, 0, stream>>>(x, w_xsq, NROWS);
    k_rownorm<<<KCODES / 256, 256, 0, stream>>>(emb, w_esq, KCODES);

    if (ws_size >= (size_t)WS_TOTAL * sizeof(float)) {
        k_emax<<<1, 1024, 0, stream>>>(w_esq, w_emax);
        k_pack<<<4096, 256, 0, stream>>>(x, xh_g, xl_g);
        k_pack<<<512, 256, 0, stream>>>(emb, eh_g, el_g);
        k_mfma<<<dim3(128, 8), 512, 0, stream>>>(xh_g, xl_g, eh_g, el_g, w_xsq, w_esq,
                                                 w_tkey, w_tm2);
        k_merge<<<128, 256, 0, stream>>>(w_tkey, w_tm2, w_xsq, w_emax, w_key, w_list, w_cnt);
        k_verify<<<2048, 256, 0, stream>>>(x, emb, w_xsq, w_esq, w_emax, w_key, w_list,
                                           w_cnt, w_dis);
        k_distrust<<<128, 256, 0, stream>>>(w_dis, w_key, w_list, w_cnt);
        k_exact<<<8192, 512, 0, stream>>>(x, emb, w_xsq, w_esq, w_list, w_cnt, w_key);
        k_finhist<<<128, 256, 0, stream>>>(w_key, w_idx, w_hist, o_ind);
    } else {
        k_argmin_full<<<NROWS / 32, 512, 0, stream>>>(x, emb, w_xsq, w_esq, w_idx);
        k_histidx<<<128, 256, 0, stream>>>(w_idx, w_hist, o_ind);
    }

    // atomic-free scatter pipeline
    k_scan<<<1, 1024, 0, stream>>>(w_hist, w_offs);
    k_place<<<128, 256, 0, stream>>>(w_idx, w_cursor, w_offs, w_rlist);
    k_esum<<<KCODES, 256, 0, stream>>>(x, w_rlist, w_offs, w_hist, w_esum);
    k_outloss<<<NROWS / 8, 256, 0, stream>>>(x, emb, w_idx, o_out, w_lpart);
    k_cluster<<<1, 1024, 0, stream>>>(cs, w_hist, o_ncs, w_n);
    k_norm<<<(KCODES * DDIM) / 256, 256, 0, stream>>>(ea, w_esum, o_ncs, w_n, o_en);
    k_loss<<<1, 256, 0, stream>>>(w_lpart, o_loss);
}